// Round 6
// baseline (291.509 us; speedup 1.0000x reference)
//
#include <hip/hip_runtime.h>
#include <math.h>

// B=4, C=64, OUT=64, H=256, W=256, M1=32, M2=32, HID=64, COORD=65

typedef __attribute__((ext_vector_type(8))) short bf16x8;
typedef __attribute__((ext_vector_type(4))) float f32x4;

__device__ __forceinline__ float gelu_f(float v) {
    return 0.5f * v * (1.0f + erff(v * 0.70710678118654752440f));
}

__device__ __forceinline__ unsigned short f2b(float f) {
    union { float f; unsigned int u; } v; v.f = f;
    unsigned int u = v.u + 0x7FFFu + ((v.u >> 16) & 1u);   // RNE
    return (unsigned short)(u >> 16);
}
__device__ __forceinline__ float b2f(unsigned short b) {
    union { unsigned int u; float f; } v; v.u = ((unsigned int)b) << 16;
    return v.f;
}

// ---------------------------------------------------------------------------
// K_prep: transpose + bf16-convert MLP weights. wT[o][k] = W[k][o]. K0 pad->96.
// ---------------------------------------------------------------------------
__global__ void k_prep(const float* __restrict__ wW0, const float* __restrict__ wW1,
                       const float* __restrict__ wW2,
                       const float* __restrict__ hW0, const float* __restrict__ hW1,
                       const float* __restrict__ hW2,
                       unsigned short* __restrict__ wT0, unsigned short* __restrict__ wT1,
                       unsigned short* __restrict__ wT2,
                       unsigned short* __restrict__ hT0, unsigned short* __restrict__ hT1,
                       unsigned short* __restrict__ hT2)
{
    const int t = threadIdx.x;
    for (int idx = t; idx < 64 * 96; idx += 256) {
        const int o = idx / 96, k = idx % 96;
        wT0[idx] = (k < 65) ? f2b(wW0[k * 64 + o]) : (unsigned short)0;
        hT0[idx] = (k < 65) ? f2b(hW0[k * 64 + o]) : (unsigned short)0;
    }
    for (int idx = t; idx < 4096; idx += 256) {
        const int o = idx >> 6, k = idx & 63;
        wT1[idx] = f2b(wW1[k * 64 + o]);
        wT2[idx] = f2b(wW2[k * 64 + o]);
        hT1[idx] = f2b(hW1[k * 64 + o]);
        hT2[idx] = f2b(hW2[k * 64 + o]);
    }
}

// generic partial-sum: dst[i] = sum_p src[p*stride + i], float4 per thread
__global__ __launch_bounds__(256) void k_psum(const float* __restrict__ src,
                                              float* __restrict__ dst,
                                              int nparts, int part_stride)
{
    const int i = (blockIdx.x * 256 + threadIdx.x) * 4;
    float4 acc = *(const float4*)&src[i];
    for (int p = 1; p < nparts; ++p) {
        const float4 v = *(const float4*)&src[(size_t)p * part_stride + i];
        acc.x += v.x; acc.y += v.y; acc.z += v.z; acc.w += v.w;
    }
    *(float4*)&dst[i] = acc;
}

// ---------------------------------------------------------------------------
// MFMA MLP layer (verified pattern)
// ---------------------------------------------------------------------------
constexpr int MLD = 104;

template<bool GELU, int NKC>
__device__ __forceinline__ void mfma_layer(
    const unsigned short* __restrict__ sW,
    const unsigned short* __restrict__ sAct,
    unsigned short* __restrict__ dst,
    const float* __restrict__ bias, int lane, int wv)
{
    const int arow = lane & 15;
    const int koff = (lane >> 4) * 8;
    const int crow = 16 * wv + (lane >> 4) * 4;
    const f32x4 zero = {0.f, 0.f, 0.f, 0.f};
    f32x4 acc[4] = {zero, zero, zero, zero};
#pragma unroll
    for (int kc = 0; kc < NKC; ++kc) {
        const bf16x8 a = *(const bf16x8*)&sW[(16 * wv + arow) * MLD + kc * 32 + koff];
#pragma unroll
        for (int nt = 0; nt < 4; ++nt) {
            const bf16x8 b = *(const bf16x8*)&sAct[(nt * 16 + arow) * MLD + kc * 32 + koff];
            acc[nt] = __builtin_amdgcn_mfma_f32_16x16x32_bf16(a, b, acc[nt], 0, 0, 0);
        }
    }
    const float4 bv = *(const float4*)&bias[crow];
#pragma unroll
    for (int nt = 0; nt < 4; ++nt) {
        const int px = nt * 16 + arow;
        float v0 = acc[nt][0] + bv.x;
        float v1 = acc[nt][1] + bv.y;
        float v2 = acc[nt][2] + bv.z;
        float v3 = acc[nt][3] + bv.w;
        if (GELU) { v0 = gelu_f(v0); v1 = gelu_f(v1); v2 = gelu_f(v2); v3 = gelu_f(v3); }
        ushort4 u;
        u.x = f2b(v0); u.y = f2b(v1); u.z = f2b(v2); u.w = f2b(v3);
        *(ushort4*)&dst[px * MLD + crow] = u;
    }
}

__device__ __forceinline__ void stage_wT96(const unsigned short* __restrict__ src,
                                           unsigned short* __restrict__ sW, int t) {
#pragma unroll
    for (int r = 0; r < 3; ++r) {
        const int idx = r * 256 + t;
        const int row = idx / 12, f = idx % 12;
        *(uint4*)&sW[row * MLD + f * 8] = *(const uint4*)&src[row * 96 + f * 8];
    }
}
__device__ __forceinline__ void stage_wT64(const unsigned short* __restrict__ src,
                                           unsigned short* __restrict__ sW, int t) {
#pragma unroll
    for (int r = 0; r < 2; ++r) {
        const int idx = r * 256 + t;
        const int row = idx >> 3, f = idx & 7;
        *(uint4*)&sW[row * MLD + f * 8] = *(const uint4*)&src[row * 64 + f * 8];
    }
}

// K1: wb basis via MFMA. grid = B*H*4. Outputs wb_bf[pix][64] AND wbT[b,h][o][w].
__global__ __launch_bounds__(256) void k_wb_mlp2(
    const float* __restrict__ x,
    const unsigned short* __restrict__ wT0, const float* __restrict__ b0,
    const unsigned short* __restrict__ wT1, const float* __restrict__ b1,
    const unsigned short* __restrict__ wT2, const float* __restrict__ b2,
    unsigned short* __restrict__ wb_bf, unsigned short* __restrict__ wbT)
{
    __shared__ __align__(16) unsigned short sA[64 * MLD];
    __shared__ __align__(16) unsigned short sB[64 * MLD];
    __shared__ __align__(16) unsigned short sW[64 * MLD];
    const int blk = blockIdx.x;
    const int b = blk >> 10, h = (blk >> 2) & 255, wq = blk & 3;
    const int w0 = wq * 64;
    const int t = threadIdx.x;
    const int lane = t & 63, wv = t >> 6;

#pragma unroll
    for (int r = 0; r < 4; ++r) {
        const int idx = r * 256 + t;
        const int c = idx >> 4, wg = idx & 15;
        const float4 v = *(const float4*)&x[((size_t)(b * 64 + c) * 256 + h) * 256 + w0 + wg * 4];
        sA[(wg * 4 + 0) * MLD + c] = f2b(v.x);
        sA[(wg * 4 + 1) * MLD + c] = f2b(v.y);
        sA[(wg * 4 + 2) * MLD + c] = f2b(v.z);
        sA[(wg * 4 + 3) * MLD + c] = f2b(v.w);
    }
    if (t < 64) {
#pragma unroll
        for (int i = 1; i < 32; ++i) sA[t * MLD + 64 + i] = 0;
        sA[t * MLD + 64] = f2b((float)(w0 + t) * (2.0f / 255.0f) - 1.0f);
    }
    stage_wT96(wT0, sW, t);
    __syncthreads();
    mfma_layer<true, 3>(sW, sA, sB, b0, lane, wv);
    __syncthreads();
    stage_wT64(wT1, sW, t);
    __syncthreads();
    mfma_layer<true, 2>(sW, sB, sA, b1, lane, wv);
    __syncthreads();
    stage_wT64(wT2, sW, t);
    __syncthreads();
    mfma_layer<false, 2>(sW, sA, sB, b2, lane, wv);
    __syncthreads();

    const size_t pixbase = (size_t)(b * 256 + h) * 256 + w0;
#pragma unroll
    for (int r = 0; r < 2; ++r) {
        const int idx = r * 256 + t;
        const int px = idx >> 3, f = idx & 7;
        *(uint4*)&wb_bf[(pixbase + px) * 64 + f * 8] = *(const uint4*)&sB[px * MLD + f * 8];
    }
    // transposed copy wbT[b,h][o][w0+..]
    const size_t tb2 = (size_t)(b * 256 + h) * 16384;
#pragma unroll
    for (int r = 0; r < 2; ++r) {
        const int idx = r * 256 + t;
        const int o = idx >> 3, g = idx & 7;
        unsigned short u[8];
#pragma unroll
        for (int j = 0; j < 8; ++j) u[j] = sB[(g * 8 + j) * MLD + o];
        *(uint4*)&wbT[tb2 + (size_t)o * 256 + w0 + g * 8] = *(uint4*)u;
    }
}

// K2: tfw via MFMA. grid = B*H (1024). D[mo][c] = sum_w wbT[mo][w]*x[c][w].
__global__ __launch_bounds__(256) void k_tfw2(
    const float* __restrict__ x,
    const unsigned short* __restrict__ wbT,
    float* __restrict__ tfwM)
{
    constexpr int TLD = 264;
    __shared__ __align__(16) unsigned short sW[64 * TLD];  // wbT rows [mo][w]
    __shared__ __align__(16) unsigned short sX[64 * TLD];  // x rows [c][w]
    const int bh = blockIdx.x;
    const int b = bh >> 8, h = bh & 255;
    const int t = threadIdx.x;
    const int lane = t & 63, wv = t >> 6;

    const size_t wtb = (size_t)bh * 16384;
#pragma unroll
    for (int r = 0; r < 8; ++r) {
        const int idx = r * 256 + t;
        const int row = idx >> 5, f = idx & 31;
        *(uint4*)&sW[row * TLD + f * 8] = *(const uint4*)&wbT[wtb + (size_t)row * 256 + f * 8];
    }
#pragma unroll
    for (int r = 0; r < 16; ++r) {
        const int idx = r * 256 + t;
        const int c = idx >> 6, f = idx & 63;
        const float4 v = *(const float4*)&x[((size_t)(b * 64 + c) * 256 + h) * 256 + f * 4];
        ushort4 u; u.x = f2b(v.x); u.y = f2b(v.y); u.z = f2b(v.z); u.w = f2b(v.w);
        *(ushort4*)&sX[c * TLD + f * 4] = u;
    }
    __syncthreads();

    const int arow = lane & 15;
    const int koff = (lane >> 4) * 8;
    const f32x4 zero = {0.f, 0.f, 0.f, 0.f};
    f32x4 acc[4] = {zero, zero, zero, zero};
#pragma unroll
    for (int kc = 0; kc < 8; ++kc) {
        const bf16x8 a = *(const bf16x8*)&sW[(16 * wv + arow) * TLD + kc * 32 + koff];
#pragma unroll
        for (int nt = 0; nt < 4; ++nt) {
            const bf16x8 bb = *(const bf16x8*)&sX[(nt * 16 + arow) * TLD + kc * 32 + koff];
            acc[nt] = __builtin_amdgcn_mfma_f32_16x16x32_bf16(a, bb, acc[nt], 0, 0, 0);
        }
    }
    __syncthreads();
    // scatter D into sW reused as f32 [mo][68]
    float* sF = (float*)sW;
    const int crow = 16 * wv + (lane >> 4) * 4;
#pragma unroll
    for (int nt = 0; nt < 4; ++nt) {
        const int c = nt * 16 + arow;
#pragma unroll
        for (int j = 0; j < 4; ++j)
            sF[(crow + j) * 68 + c] = acc[nt][j];
    }
    __syncthreads();
    // coalesced write tfwM[b][m][h][c][{re,im}]
#pragma unroll
    for (int r = 0; r < 4; ++r) {
        const int idx = r * 256 + t;
        const int m = idx >> 5, g = idx & 31;
        float4 v;
        v.x = sF[m * 68 + g * 2];
        v.y = sF[(m + 32) * 68 + g * 2];
        v.z = sF[m * 68 + g * 2 + 1];
        v.w = sF[(m + 32) * 68 + g * 2 + 1];
        *(float4*)&tfwM[((size_t)(b * 32 + m) * 256 + h) * 128 + g * 4] = v;
    }
}

// K3: hb basis via MFMA. grid = B*M2*4. out hb_bf[pix][64].
__global__ __launch_bounds__(256) void k_hb_mlp2(
    const float* __restrict__ tfwM,
    const unsigned short* __restrict__ hT0, const float* __restrict__ b0,
    const unsigned short* __restrict__ hT1, const float* __restrict__ b1,
    const unsigned short* __restrict__ hT2, const float* __restrict__ b2,
    unsigned short* __restrict__ hb_bf)
{
    __shared__ __align__(16) unsigned short sA[64 * MLD];
    __shared__ __align__(16) unsigned short sB[64 * MLD];
    __shared__ __align__(16) unsigned short sW[64 * MLD];
    const int blk = blockIdx.x;
    const int bm = blk >> 2, hq = blk & 3;
    const int h0 = hq * 64;
    const int t = threadIdx.x;
    const int lane = t & 63, wv = t >> 6;

#pragma unroll
    for (int r = 0; r < 4; ++r) {
        const int idx = r * 256 + t;
        const int p = idx >> 4, f = idx & 15;
        const float* src = &tfwM[(size_t)(bm * 256 + h0 + p) * 128 + f * 8];
        const float4 u0 = *(const float4*)&src[0];
        const float4 u1 = *(const float4*)&src[4];
        ushort4 u;
        u.x = f2b(u0.x); u.y = f2b(u0.z); u.z = f2b(u1.x); u.w = f2b(u1.z);
        *(ushort4*)&sA[p * MLD + f * 4] = u;
    }
    if (t < 64) {
#pragma unroll
        for (int i = 1; i < 32; ++i) sA[t * MLD + 64 + i] = 0;
        sA[t * MLD + 64] = f2b((float)(h0 + t) * (2.0f / 255.0f) - 1.0f);
    }
    stage_wT96(hT0, sW, t);
    __syncthreads();
    mfma_layer<true, 3>(sW, sA, sB, b0, lane, wv);
    __syncthreads();
    stage_wT64(hT1, sW, t);
    __syncthreads();
    mfma_layer<true, 2>(sW, sB, sA, b1, lane, wv);
    __syncthreads();
    stage_wT64(hT2, sW, t);
    __syncthreads();
    mfma_layer<false, 2>(sW, sA, sB, b2, lane, wv);
    __syncthreads();

    const size_t pixbase = (size_t)bm * 256 + h0;
#pragma unroll
    for (int r = 0; r < 2; ++r) {
        const int idx = r * 256 + t;
        const int px = idx >> 3, f = idx & 7;
        *(uint4*)&hb_bf[(pixbase + px) * 64 + f * 8] = *(const uint4*)&sB[px * MLD + f * 8];
    }
}

// K4: tfhw partials. grid = 1024: (bm, chalf, hq). 64 h each.
__global__ __launch_bounds__(256) void k_tfhw3(
    const float* __restrict__ tfwM,
    const unsigned short* __restrict__ hb_bf,
    float* __restrict__ tfhw_p)
{
    __shared__ float hr[64 * 32];
    __shared__ float hi2[64 * 32];
    __shared__ float slab[32 * 64];
    const int blk = blockIdx.x;
    const int bm = blk >> 3, chalf = (blk >> 2) & 1, hq = blk & 3;
    const int b = bm >> 5, m = bm & 31;
    const int t = threadIdx.x;
#pragma unroll
    for (int r = 0; r < 2; ++r) {
        const int q = r * 256 + t;
        const int hl = q >> 3, f = q & 7;
        const uint4 raw = *(const uint4*)&hb_bf[((size_t)bm * 256 + hq * 64 + hl) * 64 + f * 8];
        const unsigned short* us = (const unsigned short*)&raw;
        float v[8];
#pragma unroll
        for (int j = 0; j < 8; ++j) v[j] = b2f(us[j]);
        float* dst = (f < 4) ? &hr[hl * 32 + f * 8] : &hi2[hl * 32 + (f - 4) * 8];
        float4 lo; lo.x = v[0]; lo.y = v[1]; lo.z = v[2]; lo.w = v[3];
        float4 hi; hi.x = v[4]; hi.y = v[5]; hi.z = v[6]; hi.w = v[7];
        *(float4*)&dst[0] = lo;
        *(float4*)&dst[4] = hi;
    }
    const int k = t & 31, cq = t >> 5;
    float accr[4] = {0.f, 0.f, 0.f, 0.f}, acci[4] = {0.f, 0.f, 0.f, 0.f};
    const size_t tbase = (size_t)bm * 32768;
    for (int ht = 0; ht < 2; ++ht) {
        __syncthreads();
#pragma unroll
        for (int r = 0; r < 2; ++r) {
            const int q = r * 256 + t;
            const int hl = q >> 3, f = q & 7;
            *(float4*)&slab[hl * 64 + f * 4] =
                *(const float4*)&tfwM[tbase + (size_t)(hq * 64 + ht * 32 + hl) * 128 + chalf * 64 + f * 4];
        }
        __syncthreads();
#pragma unroll 8
        for (int hl = 0; hl < 32; ++hl) {
            const float hrv = hr[(ht * 32 + hl) * 32 + k];
            const float hiv = hi2[(ht * 32 + hl) * 32 + k];
            const float4 u0 = *(const float4*)&slab[hl * 64 + cq * 8];
            const float4 u1 = *(const float4*)&slab[hl * 64 + cq * 8 + 4];
            accr[0] = fmaf(u0.x, hrv, fmaf(-u0.y, hiv, accr[0]));
            acci[0] = fmaf(u0.x, hiv, fmaf( u0.y, hrv, acci[0]));
            accr[1] = fmaf(u0.z, hrv, fmaf(-u0.w, hiv, accr[1]));
            acci[1] = fmaf(u0.z, hiv, fmaf( u0.w, hrv, acci[1]));
            accr[2] = fmaf(u1.x, hrv, fmaf(-u1.y, hiv, accr[2]));
            acci[2] = fmaf(u1.x, hiv, fmaf( u1.y, hrv, acci[2]));
            accr[3] = fmaf(u1.z, hrv, fmaf(-u1.w, hiv, accr[3]));
            acci[3] = fmaf(u1.z, hiv, fmaf( u1.w, hrv, acci[3]));
        }
    }
    float* tp = tfhw_p + (size_t)hq * 524288;
#pragma unroll
    for (int i = 0; i < 4; ++i) {
        const int c = chalf * 32 + cq * 4 + i;
        const size_t po = ((size_t)(b * 64 + c) * 32 + k) * 32 + m;
        tp[po] = accr[i];
        tp[262144 + po] = acci[i];
    }
}

// K5: proc partials. grid = 512: (o, kq, chalf).
__global__ __launch_bounds__(256) void k_proc2(
    const float* __restrict__ tfhw,   // re || im
    const float* __restrict__ Wf_re, const float* __restrict__ Wf_im,
    float* __restrict__ proc_p)
{
    const int blk = blockIdx.x;
    const int o = blk >> 3, kq = (blk >> 1) & 3, chalf = blk & 1;
    const int t = threadIdx.x;
    const int mo = kq * 256 + t;
    const float* tre = tfhw;
    const float* tim = tfhw + 262144;
    float accr[4] = {0.f, 0.f, 0.f, 0.f}, acci[4] = {0.f, 0.f, 0.f, 0.f};
    for (int cc = 0; cc < 32; ++cc) {
        const int c = chalf * 32 + cc;
        const float wfr = Wf_re[(size_t)(c * 64 + o) * 1024 + mo];
        const float wfi = Wf_im[(size_t)(c * 64 + o) * 1024 + mo];
#pragma unroll
        for (int bb = 0; bb < 4; ++bb) {
            const float tr = tre[(size_t)(bb * 64 + c) * 1024 + mo];
            const float ti = tim[(size_t)(bb * 64 + c) * 1024 + mo];
            accr[bb] = fmaf(tr, wfr, fmaf(-ti, wfi, accr[bb]));
            acci[bb] = fmaf(tr, wfi, fmaf(ti, wfr, acci[bb]));
        }
    }
    float* pp = proc_p + (size_t)chalf * 524288;
#pragma unroll
    for (int bb = 0; bb < 4; ++bb) {
        pp[(size_t)(bb * 64 + o) * 1024 + mo] = accr[bb];
        pp[262144 + (size_t)(bb * 64 + o) * 1024 + mo] = acci[bb];
    }
}

// K6: recO bf16. grid = 1024: (bm, hq8). 32 h each.
__global__ __launch_bounds__(256) void k_rec2(
    const float* __restrict__ proc,   // re || im
    const unsigned short* __restrict__ hb_bf,
    unsigned short* __restrict__ recO)
{
    __shared__ float lhr[32 * 32];
    __shared__ float lhi[32 * 32];
    const int blk = blockIdx.x;
    const int bm = blk >> 3, hq = blk & 7;
    const int b = bm >> 5, m = bm & 31;
    const int t = threadIdx.x;
    {
        const int hl = t >> 3, f = t & 7;
        const uint4 raw = *(const uint4*)&hb_bf[((size_t)bm * 256 + hq * 32 + hl) * 64 + f * 8];
        const unsigned short* us = (const unsigned short*)&raw;
        float v[8];
#pragma unroll
        for (int j = 0; j < 8; ++j) v[j] = b2f(us[j]);
        float* dst = (f < 4) ? &lhr[hl * 32 + f * 8] : &lhi[hl * 32 + (f - 4) * 8];
        float4 lo; lo.x = v[0]; lo.y = v[1]; lo.z = v[2]; lo.w = v[3];
        float4 hi; hi.x = v[4]; hi.y = v[5]; hi.z = v[6]; hi.w = v[7];
        *(float4*)&dst[0] = lo;
        *(float4*)&dst[4] = hi;
    }
    const int o = t & 63, hg = t >> 6;
    const float* proc_re = proc;
    const float* proc_im = proc + 262144;
    float Pr[32], Pi[32];
#pragma unroll
    for (int k = 0; k < 32; ++k) {
        const size_t pa = ((size_t)(b * 64 + o) * 32 + k) * 32 + m;
        Pr[k] = proc_re[pa];
        Pi[k] = proc_im[pa];
    }
    __syncthreads();
    for (int hh = 0; hh < 8; ++hh) {
        const int hl = hg * 8 + hh;
        float ar = 0.f, ai = 0.f;
#pragma unroll
        for (int k = 0; k < 32; ++k) {
            const float hrv = lhr[hl * 32 + k], hiv = lhi[hl * 32 + k];
            ar = fmaf(Pr[k], hrv, fmaf(Pi[k], hiv, ar));
            ai = fmaf(Pi[k], hrv, fmaf(-Pr[k], hiv, ai));
        }
        const int h = hq * 32 + hl;
        const size_t rb = ((size_t)(b * 256 + h) * 64 + o) * 64;
        recO[rb + m]      = f2b(ar);
        recO[rb + 32 + m] = f2b(ai);
    }
}

// K7: MFMA fused final. grid = B*H*4.
__global__ __launch_bounds__(256) void k_final4(
    const float* __restrict__ x,
    const unsigned short* __restrict__ wb_bf,
    const unsigned short* __restrict__ recO,
    const float* __restrict__ mw, const float* __restrict__ mb,
    const float* __restrict__ scw, const float* __restrict__ scb,
    float* __restrict__ out)
{
    constexpr int LD = 72;
    __shared__ __align__(16) unsigned short sWb[64 * LD];
    __shared__ __align__(16) unsigned short sR [64 * LD];
    __shared__ __align__(16) unsigned short sX [64 * LD];
    __shared__ __align__(16) unsigned short sS [64 * LD];
    const int blk = blockIdx.x;
    const int b = blk >> 10, h = (blk >> 2) & 255, wq = blk & 3;
    const int w0 = wq * 64;
    const int t = threadIdx.x;
    const int lane = t & 63, wv = t >> 6;
    const size_t pixbase = (size_t)(b * 256 + h) * 256 + w0;

#pragma unroll
    for (int r = 0; r < 2; ++r) {
        const int idx = r * 256 + t;
        const int px = idx >> 3, f = idx & 7;
        *(uint4*)&sWb[px * LD + f * 8] = *(const uint4*)&wb_bf[(pixbase + px) * 64 + f * 8];
    }
    const size_t recbase = (size_t)(b * 256 + h) * 4096;
#pragma unroll
    for (int r = 0; r < 2; ++r) {
        const int idx = r * 256 + t;
        const int o = idx >> 3, f = idx & 7;
        *(uint4*)&sR[o * LD + f * 8] = *(const uint4*)&recO[recbase + (size_t)o * 64 + f * 8];
    }
#pragma unroll
    for (int r = 0; r < 4; ++r) {
        const int idx = r * 256 + t;
        const int c = idx >> 4, wg = idx & 15;
        const float4 v = *(const float4*)&x[((size_t)(b * 64 + c) * 256 + h) * 256 + w0 + wg * 4];
        sX[(wg * 4 + 0) * LD + c] = f2b(v.x);
        sX[(wg * 4 + 1) * LD + c] = f2b(v.y);
        sX[(wg * 4 + 2) * LD + c] = f2b(v.z);
        sX[(wg * 4 + 3) * LD + c] = f2b(v.w);
    }
    __syncthreads();

    const int arow = lane & 15;
    const int koff = (lane >> 4) * 8;
    const f32x4 zero = {0.f, 0.f, 0.f, 0.f};

    f32x4 accA[4] = {zero, zero, zero, zero};
#pragma unroll
    for (int kc = 0; kc < 2; ++kc) {
        const bf16x8 a = *(const bf16x8*)&sR[(16 * wv + arow) * LD + kc * 32 + koff];
#pragma unroll
        for (int nt = 0; nt < 4; ++nt) {
            const bf16x8 bb = *(const bf16x8*)&sWb[(nt * 16 + arow) * LD + kc * 32 + koff];
            accA[nt] = __builtin_amdgcn_mfma_f32_16x16x32_bf16(a, bb, accA[nt], 0, 0, 0);
        }
    }
    __syncthreads();

    const int crow = 16 * wv + (lane >> 4) * 4;
#pragma unroll
    for (int nt = 0; nt < 4; ++nt) {
        const int px = nt * 16 + arow;
#pragma unroll
        for (int j = 0; j < 4; ++j)
            sS[px * LD + crow + j] = f2b(accA[nt][j] * (1.0f / 65536.0f));
    }
#pragma unroll
    for (int r = 0; r < 4; ++r) {
        const int idx = r * 256 + t;
        const int o = idx >> 4, cq = idx & 15;
        const float4 v1 = *(const float4*)&mw[o * 64 + cq * 4];
        ushort4 u1;
        u1.x = f2b(v1.x); u1.y = f2b(v1.y); u1.z = f2b(v1.z); u1.w = f2b(v1.w);
        *(ushort4*)&sWb[o * LD + cq * 4] = u1;
        const float4 v2 = *(const float4*)&scw[o * 64 + cq * 4];
        ushort4 u2;
        u2.x = f2b(v2.x); u2.y = f2b(v2.y); u2.z = f2b(v2.z); u2.w = f2b(v2.w);
        *(ushort4*)&sR[o * LD + cq * 4] = u2;
    }
    __syncthreads();

    f32x4 accB[4] = {zero, zero, zero, zero};
    f32x4 accC[4] = {zero, zero, zero, zero};
#pragma unroll
    for (int kc = 0; kc < 2; ++kc) {
        const bf16x8 am = *(const bf16x8*)&sWb[(16 * wv + arow) * LD + kc * 32 + koff];
        const bf16x8 as = *(const bf16x8*)&sR [(16 * wv + arow) * LD + kc * 32 + koff];
#pragma unroll
        for (int nt = 0; nt < 4; ++nt) {
            const bf16x8 bs = *(const bf16x8*)&sS[(nt * 16 + arow) * LD + kc * 32 + koff];
            const bf16x8 bx = *(const bf16x8*)&sX[(nt * 16 + arow) * LD + kc * 32 + koff];
            accB[nt] = __builtin_amdgcn_mfma_f32_16x16x32_bf16(am, bs, accB[nt], 0, 0, 0);
            accC[nt] = __builtin_amdgcn_mfma_f32_16x16x32_bf16(as, bx, accC[nt], 0, 0, 0);
        }
    }

#pragma unroll
    for (int nt = 0; nt < 4; ++nt) {
        const int px = nt * 16 + arow;
#pragma unroll
        for (int j = 0; j < 4; ++j) {
            const int o = crow + j;
            const float y = gelu_f(accB[nt][j] + mb[o]);
            const float z = y + accC[nt][j] + scb[o];
            out[((size_t)(b * 64 + o) * 256 + h) * 256 + w0 + px] = gelu_f(z);
        }
    }
}

extern "C" void kernel_launch(void* const* d_in, const int* in_sizes, int n_in,
                              void* d_out, int out_size, void* d_ws, size_t ws_size,
                              hipStream_t stream) {
    const float* x    = (const float*)d_in[0];
    const float* wW0  = (const float*)d_in[1];
    const float* wb0  = (const float*)d_in[2];
    const float* wW1  = (const float*)d_in[3];
    const float* wb1  = (const float*)d_in[4];
    const float* wW2  = (const float*)d_in[5];
    const float* wb2  = (const float*)d_in[6];
    const float* hW0  = (const float*)d_in[7];
    const float* hb0  = (const float*)d_in[8];
    const float* hW1  = (const float*)d_in[9];
    const float* hb1  = (const float*)d_in[10];
    const float* hW2  = (const float*)d_in[11];
    const float* hb2  = (const float*)d_in[12];
    const float* Wf_re = (const float*)d_in[13];
    const float* Wf_im = (const float*)d_in[14];
    const float* mw   = (const float*)d_in[15];
    const float* mbv  = (const float*)d_in[16];
    const float* scw  = (const float*)d_in[17];
    const float* scb  = (const float*)d_in[18];

    char* base = (char*)d_ws;
    unsigned short* wb_bf = (unsigned short*)(base + 0);            // 33,554,432
    unsigned short* wbT   = (unsigned short*)(base + 33554432);     // 33,554,432
    float* tfwM   = (float*)(base + 67108864);                      // 16,777,216
    unsigned short* hb_bf = (unsigned short*)(base + 83886080);     //  4,194,304
    float* tfhw_p = (float*)(base + 88080384);                      //  8,388,608 (4 parts)
    float* tfhw   = (float*)(base + 96468992);                      //  2,097,152 (re||im)
    float* proc_p = (float*)(base + 98566144);                      //  4,194,304 (2 parts)
    float* proc   = (float*)(base + 102760448);                     //  2,097,152 (re||im)
    unsigned short* recO = (unsigned short*)(base + 104857600);     //  8,388,608
    unsigned short* wT0 = (unsigned short*)(base + 113246208);
    unsigned short* wT1 = (unsigned short*)(base + 113258496);
    unsigned short* wT2 = (unsigned short*)(base + 113266688);
    unsigned short* hT0 = (unsigned short*)(base + 113274880);
    unsigned short* hT1 = (unsigned short*)(base + 113287168);
    unsigned short* hT2 = (unsigned short*)(base + 113295360);
    // total ~113.3 MB

    k_prep<<<1, 256, 0, stream>>>(wW0, wW1, wW2, hW0, hW1, hW2,
                                  wT0, wT1, wT2, hT0, hT1, hT2);
    k_wb_mlp2<<<4096, 256, 0, stream>>>(x, wT0, wb0, wT1, wb1, wT2, wb2, wb_bf, wbT);
    k_tfw2<<<1024, 256, 0, stream>>>(x, wbT, tfwM);
    k_hb_mlp2<<<512, 256, 0, stream>>>(tfwM, hT0, hb0, hT1, hb1, hT2, hb2, hb_bf);
    k_tfhw3<<<1024, 256, 0, stream>>>(tfwM, hb_bf, tfhw_p);
    k_psum<<<1024, 256, 0, stream>>>(tfhw_p, tfhw, 4, 524288);
    k_proc2<<<512, 256, 0, stream>>>(tfhw, Wf_re, Wf_im, proc_p);
    k_psum<<<512, 256, 0, stream>>>(proc_p, proc, 2, 524288);
    k_rec2<<<1024, 256, 0, stream>>>(proc, hb_bf, recO);
    k_final4<<<4096, 256, 0, stream>>>(x, wb_bf, recO, mw, mbv, scw, scb, (float*)d_out);
}

// Round 7
// 209.456 us; speedup vs baseline: 1.3917x; 1.3917x over previous
//
#include <hip/hip_runtime.h>
#include <math.h>

// B=4, C=64, OUT=64, H=256, W=256, M1=32, M2=32, HID=64, COORD=65

typedef __attribute__((ext_vector_type(8))) short bf16x8;
typedef __attribute__((ext_vector_type(4))) float f32x4;

__device__ __forceinline__ float gelu_f(float v) {
    return 0.5f * v * (1.0f + erff(v * 0.70710678118654752440f));
}

__device__ __forceinline__ unsigned short f2b(float f) {
    union { float f; unsigned int u; } v; v.f = f;
    unsigned int u = v.u + 0x7FFFu + ((v.u >> 16) & 1u);   // RNE
    return (unsigned short)(u >> 16);
}
__device__ __forceinline__ float b2f(unsigned short b) {
    union { unsigned int u; float f; } v; v.u = ((unsigned int)b) << 16;
    return v.f;
}

// ---------------------------------------------------------------------------
// K_prep: transpose + bf16-convert MLP weights. wT[o][k] = W[k][o]. K0 pad->96.
// ---------------------------------------------------------------------------
__global__ void k_prep(const float* __restrict__ wW0, const float* __restrict__ wW1,
                       const float* __restrict__ wW2,
                       const float* __restrict__ hW0, const float* __restrict__ hW1,
                       const float* __restrict__ hW2,
                       unsigned short* __restrict__ wT0, unsigned short* __restrict__ wT1,
                       unsigned short* __restrict__ wT2,
                       unsigned short* __restrict__ hT0, unsigned short* __restrict__ hT1,
                       unsigned short* __restrict__ hT2)
{
    const int t = threadIdx.x;
    for (int idx = t; idx < 64 * 96; idx += 256) {
        const int o = idx / 96, k = idx % 96;
        wT0[idx] = (k < 65) ? f2b(wW0[k * 64 + o]) : (unsigned short)0;
        hT0[idx] = (k < 65) ? f2b(hW0[k * 64 + o]) : (unsigned short)0;
    }
    for (int idx = t; idx < 4096; idx += 256) {
        const int o = idx >> 6, k = idx & 63;
        wT1[idx] = f2b(wW1[k * 64 + o]);
        wT2[idx] = f2b(wW2[k * 64 + o]);
        hT1[idx] = f2b(hW1[k * 64 + o]);
        hT2[idx] = f2b(hW2[k * 64 + o]);
    }
}

// generic partial-sum: dst[i] = sum_p src[p*stride + i], float4 per thread
__global__ __launch_bounds__(256) void k_psum(const float* __restrict__ src,
                                              float* __restrict__ dst,
                                              int nparts, int part_stride)
{
    const int i = (blockIdx.x * 256 + threadIdx.x) * 4;
    float4 acc = *(const float4*)&src[i];
    for (int p = 1; p < nparts; ++p) {
        const float4 v = *(const float4*)&src[(size_t)p * part_stride + i];
        acc.x += v.x; acc.y += v.y; acc.z += v.z; acc.w += v.w;
    }
    *(float4*)&dst[i] = acc;
}

// psum for proc + repack to procT[((b*32+m)*32+k)*64+o] (re || im at +262144).
// grid = 1024.
__global__ __launch_bounds__(256) void k_psum_procT(const float* __restrict__ src,
                                                    float* __restrict__ dst)
{
    const int idx = blockIdx.x * 256 + threadIdx.x;       // 0..262143
    const int o = idx & 63, k = (idx >> 6) & 31, m = (idx >> 11) & 31, b = idx >> 16;
    const size_t in = (size_t)(b * 64 + o) * 1024 + k * 32 + m;
    const float re = src[in] + src[524288 + in];
    const float im = src[262144 + in] + src[524288 + 262144 + in];
    dst[idx] = re;
    dst[262144 + idx] = im;
}

// ---------------------------------------------------------------------------
// MFMA MLP layer (verified pattern)
// ---------------------------------------------------------------------------
constexpr int MLD = 104;

template<bool GELU, int NKC>
__device__ __forceinline__ void mfma_layer(
    const unsigned short* __restrict__ sW,
    const unsigned short* __restrict__ sAct,
    unsigned short* __restrict__ dst,
    const float* __restrict__ bias, int lane, int wv)
{
    const int arow = lane & 15;
    const int koff = (lane >> 4) * 8;
    const int crow = 16 * wv + (lane >> 4) * 4;
    const f32x4 zero = {0.f, 0.f, 0.f, 0.f};
    f32x4 acc[4] = {zero, zero, zero, zero};
#pragma unroll
    for (int kc = 0; kc < NKC; ++kc) {
        const bf16x8 a = *(const bf16x8*)&sW[(16 * wv + arow) * MLD + kc * 32 + koff];
#pragma unroll
        for (int nt = 0; nt < 4; ++nt) {
            const bf16x8 b = *(const bf16x8*)&sAct[(nt * 16 + arow) * MLD + kc * 32 + koff];
            acc[nt] = __builtin_amdgcn_mfma_f32_16x16x32_bf16(a, b, acc[nt], 0, 0, 0);
        }
    }
    const float4 bv = *(const float4*)&bias[crow];
#pragma unroll
    for (int nt = 0; nt < 4; ++nt) {
        const int px = nt * 16 + arow;
        float v0 = acc[nt][0] + bv.x;
        float v1 = acc[nt][1] + bv.y;
        float v2 = acc[nt][2] + bv.z;
        float v3 = acc[nt][3] + bv.w;
        if (GELU) { v0 = gelu_f(v0); v1 = gelu_f(v1); v2 = gelu_f(v2); v3 = gelu_f(v3); }
        ushort4 u;
        u.x = f2b(v0); u.y = f2b(v1); u.z = f2b(v2); u.w = f2b(v3);
        *(ushort4*)&dst[px * MLD + crow] = u;
    }
}

__device__ __forceinline__ void stage_wT96(const unsigned short* __restrict__ src,
                                           unsigned short* __restrict__ sW, int t) {
#pragma unroll
    for (int r = 0; r < 3; ++r) {
        const int idx = r * 256 + t;
        const int row = idx / 12, f = idx % 12;
        *(uint4*)&sW[row * MLD + f * 8] = *(const uint4*)&src[row * 96 + f * 8];
    }
}
__device__ __forceinline__ void stage_wT64(const unsigned short* __restrict__ src,
                                           unsigned short* __restrict__ sW, int t) {
#pragma unroll
    for (int r = 0; r < 2; ++r) {
        const int idx = r * 256 + t;
        const int row = idx >> 3, f = idx & 7;
        *(uint4*)&sW[row * MLD + f * 8] = *(const uint4*)&src[row * 64 + f * 8];
    }
}

// K1: wb basis via MFMA. grid = B*H*4. Outputs wb_bf[pix][64] AND wbT[b,h][o][w].
__global__ __launch_bounds__(256) void k_wb_mlp2(
    const float* __restrict__ x,
    const unsigned short* __restrict__ wT0, const float* __restrict__ b0,
    const unsigned short* __restrict__ wT1, const float* __restrict__ b1,
    const unsigned short* __restrict__ wT2, const float* __restrict__ b2,
    unsigned short* __restrict__ wb_bf, unsigned short* __restrict__ wbT)
{
    __shared__ __align__(16) unsigned short sA[64 * MLD];
    __shared__ __align__(16) unsigned short sB[64 * MLD];
    __shared__ __align__(16) unsigned short sW[64 * MLD];
    const int blk = blockIdx.x;
    const int b = blk >> 10, h = (blk >> 2) & 255, wq = blk & 3;
    const int w0 = wq * 64;
    const int t = threadIdx.x;
    const int lane = t & 63, wv = t >> 6;

#pragma unroll
    for (int r = 0; r < 4; ++r) {
        const int idx = r * 256 + t;
        const int c = idx >> 4, wg = idx & 15;
        const float4 v = *(const float4*)&x[((size_t)(b * 64 + c) * 256 + h) * 256 + w0 + wg * 4];
        sA[(wg * 4 + 0) * MLD + c] = f2b(v.x);
        sA[(wg * 4 + 1) * MLD + c] = f2b(v.y);
        sA[(wg * 4 + 2) * MLD + c] = f2b(v.z);
        sA[(wg * 4 + 3) * MLD + c] = f2b(v.w);
    }
    if (t < 64) {
#pragma unroll
        for (int i = 1; i < 32; ++i) sA[t * MLD + 64 + i] = 0;
        sA[t * MLD + 64] = f2b((float)(w0 + t) * (2.0f / 255.0f) - 1.0f);
    }
    stage_wT96(wT0, sW, t);
    __syncthreads();
    mfma_layer<true, 3>(sW, sA, sB, b0, lane, wv);
    __syncthreads();
    stage_wT64(wT1, sW, t);
    __syncthreads();
    mfma_layer<true, 2>(sW, sB, sA, b1, lane, wv);
    __syncthreads();
    stage_wT64(wT2, sW, t);
    __syncthreads();
    mfma_layer<false, 2>(sW, sA, sB, b2, lane, wv);
    __syncthreads();

    const size_t pixbase = (size_t)(b * 256 + h) * 256 + w0;
#pragma unroll
    for (int r = 0; r < 2; ++r) {
        const int idx = r * 256 + t;
        const int px = idx >> 3, f = idx & 7;
        *(uint4*)&wb_bf[(pixbase + px) * 64 + f * 8] = *(const uint4*)&sB[px * MLD + f * 8];
    }
    // transposed copy wbT[b,h][o][w0+..]
    const size_t tb2 = (size_t)(b * 256 + h) * 16384;
#pragma unroll
    for (int r = 0; r < 2; ++r) {
        const int idx = r * 256 + t;
        const int o = idx >> 3, g = idx & 7;
        unsigned short u[8];
#pragma unroll
        for (int j = 0; j < 8; ++j) u[j] = sB[(g * 8 + j) * MLD + o];
        *(uint4*)&wbT[tb2 + (size_t)o * 256 + w0 + g * 8] = *(uint4*)u;
    }
}

// K2: tfw via MFMA. grid = B*H (1024). D[mo][c] = sum_w wbT[mo][w]*x[c][w].
__global__ __launch_bounds__(256) void k_tfw2(
    const float* __restrict__ x,
    const unsigned short* __restrict__ wbT,
    float* __restrict__ tfwM)
{
    constexpr int TLD = 264;
    __shared__ __align__(16) unsigned short sW[64 * TLD];  // wbT rows [mo][w]
    __shared__ __align__(16) unsigned short sX[64 * TLD];  // x rows [c][w]
    const int bh = blockIdx.x;
    const int b = bh >> 8, h = bh & 255;
    const int t = threadIdx.x;
    const int lane = t & 63, wv = t >> 6;

    const size_t wtb = (size_t)bh * 16384;
#pragma unroll
    for (int r = 0; r < 8; ++r) {
        const int idx = r * 256 + t;
        const int row = idx >> 5, f = idx & 31;
        *(uint4*)&sW[row * TLD + f * 8] = *(const uint4*)&wbT[wtb + (size_t)row * 256 + f * 8];
    }
#pragma unroll
    for (int r = 0; r < 16; ++r) {
        const int idx = r * 256 + t;
        const int c = idx >> 6, f = idx & 63;
        const float4 v = *(const float4*)&x[((size_t)(b * 64 + c) * 256 + h) * 256 + f * 4];
        ushort4 u; u.x = f2b(v.x); u.y = f2b(v.y); u.z = f2b(v.z); u.w = f2b(v.w);
        *(ushort4*)&sX[c * TLD + f * 4] = u;
    }
    __syncthreads();

    const int arow = lane & 15;
    const int koff = (lane >> 4) * 8;
    const f32x4 zero = {0.f, 0.f, 0.f, 0.f};
    f32x4 acc[4] = {zero, zero, zero, zero};
#pragma unroll
    for (int kc = 0; kc < 8; ++kc) {
        const bf16x8 a = *(const bf16x8*)&sW[(16 * wv + arow) * TLD + kc * 32 + koff];
#pragma unroll
        for (int nt = 0; nt < 4; ++nt) {
            const bf16x8 bb = *(const bf16x8*)&sX[(nt * 16 + arow) * TLD + kc * 32 + koff];
            acc[nt] = __builtin_amdgcn_mfma_f32_16x16x32_bf16(a, bb, acc[nt], 0, 0, 0);
        }
    }
    __syncthreads();
    // scatter D into sW reused as f32 [mo][68]
    float* sF = (float*)sW;
    const int crow = 16 * wv + (lane >> 4) * 4;
#pragma unroll
    for (int nt = 0; nt < 4; ++nt) {
        const int c = nt * 16 + arow;
#pragma unroll
        for (int j = 0; j < 4; ++j)
            sF[(crow + j) * 68 + c] = acc[nt][j];
    }
    __syncthreads();
    // coalesced write tfwM[b][m][h][c][{re,im}]
#pragma unroll
    for (int r = 0; r < 4; ++r) {
        const int idx = r * 256 + t;
        const int m = idx >> 5, g = idx & 31;
        float4 v;
        v.x = sF[m * 68 + g * 2];
        v.y = sF[(m + 32) * 68 + g * 2];
        v.z = sF[m * 68 + g * 2 + 1];
        v.w = sF[(m + 32) * 68 + g * 2 + 1];
        *(float4*)&tfwM[((size_t)(b * 32 + m) * 256 + h) * 128 + g * 4] = v;
    }
}

// K3: hb basis via MFMA. grid = B*M2*4. out hb_bf[pix][64].
__global__ __launch_bounds__(256) void k_hb_mlp2(
    const float* __restrict__ tfwM,
    const unsigned short* __restrict__ hT0, const float* __restrict__ b0,
    const unsigned short* __restrict__ hT1, const float* __restrict__ b1,
    const unsigned short* __restrict__ hT2, const float* __restrict__ b2,
    unsigned short* __restrict__ hb_bf)
{
    __shared__ __align__(16) unsigned short sA[64 * MLD];
    __shared__ __align__(16) unsigned short sB[64 * MLD];
    __shared__ __align__(16) unsigned short sW[64 * MLD];
    const int blk = blockIdx.x;
    const int bm = blk >> 2, hq = blk & 3;
    const int h0 = hq * 64;
    const int t = threadIdx.x;
    const int lane = t & 63, wv = t >> 6;

#pragma unroll
    for (int r = 0; r < 4; ++r) {
        const int idx = r * 256 + t;
        const int p = idx >> 4, f = idx & 15;
        const float* src = &tfwM[(size_t)(bm * 256 + h0 + p) * 128 + f * 8];
        const float4 u0 = *(const float4*)&src[0];
        const float4 u1 = *(const float4*)&src[4];
        ushort4 u;
        u.x = f2b(u0.x); u.y = f2b(u0.z); u.z = f2b(u1.x); u.w = f2b(u1.z);
        *(ushort4*)&sA[p * MLD + f * 4] = u;
    }
    if (t < 64) {
#pragma unroll
        for (int i = 1; i < 32; ++i) sA[t * MLD + 64 + i] = 0;
        sA[t * MLD + 64] = f2b((float)(h0 + t) * (2.0f / 255.0f) - 1.0f);
    }
    stage_wT96(hT0, sW, t);
    __syncthreads();
    mfma_layer<true, 3>(sW, sA, sB, b0, lane, wv);
    __syncthreads();
    stage_wT64(hT1, sW, t);
    __syncthreads();
    mfma_layer<true, 2>(sW, sB, sA, b1, lane, wv);
    __syncthreads();
    stage_wT64(hT2, sW, t);
    __syncthreads();
    mfma_layer<false, 2>(sW, sA, sB, b2, lane, wv);
    __syncthreads();

    const size_t pixbase = (size_t)bm * 256 + h0;
#pragma unroll
    for (int r = 0; r < 2; ++r) {
        const int idx = r * 256 + t;
        const int px = idx >> 3, f = idx & 7;
        *(uint4*)&hb_bf[(pixbase + px) * 64 + f * 8] = *(const uint4*)&sB[px * MLD + f * 8];
    }
}

// K4: tfhw partials. grid = 1024: (bm, chalf, hq). 64 h each.
__global__ __launch_bounds__(256) void k_tfhw3(
    const float* __restrict__ tfwM,
    const unsigned short* __restrict__ hb_bf,
    float* __restrict__ tfhw_p)
{
    __shared__ float hr[64 * 32];
    __shared__ float hi2[64 * 32];
    __shared__ float slab[32 * 64];
    const int blk = blockIdx.x;
    const int bm = blk >> 3, chalf = (blk >> 2) & 1, hq = blk & 3;
    const int b = bm >> 5, m = bm & 31;
    const int t = threadIdx.x;
#pragma unroll
    for (int r = 0; r < 2; ++r) {
        const int q = r * 256 + t;
        const int hl = q >> 3, f = q & 7;
        const uint4 raw = *(const uint4*)&hb_bf[((size_t)bm * 256 + hq * 64 + hl) * 64 + f * 8];
        const unsigned short* us = (const unsigned short*)&raw;
        float v[8];
#pragma unroll
        for (int j = 0; j < 8; ++j) v[j] = b2f(us[j]);
        float* dst = (f < 4) ? &hr[hl * 32 + f * 8] : &hi2[hl * 32 + (f - 4) * 8];
        float4 lo; lo.x = v[0]; lo.y = v[1]; lo.z = v[2]; lo.w = v[3];
        float4 hi; hi.x = v[4]; hi.y = v[5]; hi.z = v[6]; hi.w = v[7];
        *(float4*)&dst[0] = lo;
        *(float4*)&dst[4] = hi;
    }
    const int k = t & 31, cq = t >> 5;
    float accr[4] = {0.f, 0.f, 0.f, 0.f}, acci[4] = {0.f, 0.f, 0.f, 0.f};
    const size_t tbase = (size_t)bm * 32768;
    for (int ht = 0; ht < 2; ++ht) {
        __syncthreads();
#pragma unroll
        for (int r = 0; r < 2; ++r) {
            const int q = r * 256 + t;
            const int hl = q >> 3, f = q & 7;
            *(float4*)&slab[hl * 64 + f * 4] =
                *(const float4*)&tfwM[tbase + (size_t)(hq * 64 + ht * 32 + hl) * 128 + chalf * 64 + f * 4];
        }
        __syncthreads();
#pragma unroll 8
        for (int hl = 0; hl < 32; ++hl) {
            const float hrv = hr[(ht * 32 + hl) * 32 + k];
            const float hiv = hi2[(ht * 32 + hl) * 32 + k];
            const float4 u0 = *(const float4*)&slab[hl * 64 + cq * 8];
            const float4 u1 = *(const float4*)&slab[hl * 64 + cq * 8 + 4];
            accr[0] = fmaf(u0.x, hrv, fmaf(-u0.y, hiv, accr[0]));
            acci[0] = fmaf(u0.x, hiv, fmaf( u0.y, hrv, acci[0]));
            accr[1] = fmaf(u0.z, hrv, fmaf(-u0.w, hiv, accr[1]));
            acci[1] = fmaf(u0.z, hiv, fmaf( u0.w, hrv, acci[1]));
            accr[2] = fmaf(u1.x, hrv, fmaf(-u1.y, hiv, accr[2]));
            acci[2] = fmaf(u1.x, hiv, fmaf( u1.y, hrv, acci[2]));
            accr[3] = fmaf(u1.z, hrv, fmaf(-u1.w, hiv, accr[3]));
            acci[3] = fmaf(u1.z, hiv, fmaf( u1.w, hrv, acci[3]));
        }
    }
    float* tp = tfhw_p + (size_t)hq * 524288;
#pragma unroll
    for (int i = 0; i < 4; ++i) {
        const int c = chalf * 32 + cq * 4 + i;
        const size_t po = ((size_t)(b * 64 + c) * 32 + k) * 32 + m;
        tp[po] = accr[i];
        tp[262144 + po] = acci[i];
    }
}

// K5: proc partials. grid = 512: (o, kq, chalf).
__global__ __launch_bounds__(256) void k_proc2(
    const float* __restrict__ tfhw,   // re || im
    const float* __restrict__ Wf_re, const float* __restrict__ Wf_im,
    float* __restrict__ proc_p)
{
    const int blk = blockIdx.x;
    const int o = blk >> 3, kq = (blk >> 1) & 3, chalf = blk & 1;
    const int t = threadIdx.x;
    const int mo = kq * 256 + t;
    const float* tre = tfhw;
    const float* tim = tfhw + 262144;
    float accr[4] = {0.f, 0.f, 0.f, 0.f}, acci[4] = {0.f, 0.f, 0.f, 0.f};
    for (int cc = 0; cc < 32; ++cc) {
        const int c = chalf * 32 + cc;
        const float wfr = Wf_re[(size_t)(c * 64 + o) * 1024 + mo];
        const float wfi = Wf_im[(size_t)(c * 64 + o) * 1024 + mo];
#pragma unroll
        for (int bb = 0; bb < 4; ++bb) {
            const float tr = tre[(size_t)(bb * 64 + c) * 1024 + mo];
            const float ti = tim[(size_t)(bb * 64 + c) * 1024 + mo];
            accr[bb] = fmaf(tr, wfr, fmaf(-ti, wfi, accr[bb]));
            acci[bb] = fmaf(tr, wfi, fmaf(ti, wfr, acci[bb]));
        }
    }
    float* pp = proc_p + (size_t)chalf * 524288;
#pragma unroll
    for (int bb = 0; bb < 4; ++bb) {
        pp[(size_t)(bb * 64 + o) * 1024 + mo] = accr[bb];
        pp[262144 + (size_t)(bb * 64 + o) * 1024 + mo] = acci[bb];
    }
}

// K6: recO bf16. grid = 1024: (bm, hq8). 32 h each. Coalesced procT reads.
__global__ __launch_bounds__(256) void k_rec4(
    const float* __restrict__ procT,   // re || im, [((b*32+m)*32+k)*64+o]
    const unsigned short* __restrict__ hb_bf,
    unsigned short* __restrict__ recO)
{
    __shared__ float lhr[32 * 32];
    __shared__ float lhi[32 * 32];
    const int blk = blockIdx.x;
    const int bm = blk >> 3, hq = blk & 7;
    const int b = bm >> 5, m = bm & 31;
    const int t = threadIdx.x;
    {
        const int hl = t >> 3, f = t & 7;
        const uint4 raw = *(const uint4*)&hb_bf[((size_t)bm * 256 + hq * 32 + hl) * 64 + f * 8];
        const unsigned short* us = (const unsigned short*)&raw;
        float v[8];
#pragma unroll
        for (int j = 0; j < 8; ++j) v[j] = b2f(us[j]);
        float* dst = (f < 4) ? &lhr[hl * 32 + f * 8] : &lhi[hl * 32 + (f - 4) * 8];
        float4 lo; lo.x = v[0]; lo.y = v[1]; lo.z = v[2]; lo.w = v[3];
        float4 hi; hi.x = v[4]; hi.y = v[5]; hi.z = v[6]; hi.w = v[7];
        *(float4*)&dst[0] = lo;
        *(float4*)&dst[4] = hi;
    }
    const int o = t & 63, hg = t >> 6;
    const float* pr = procT + (size_t)(b * 32 + m) * 2048 + o;
    const float* pi = pr + 262144;
    float Pr[32], Pi[32];
#pragma unroll
    for (int k = 0; k < 32; ++k) {
        Pr[k] = pr[k * 64];     // consecutive lanes -> consecutive addresses
        Pi[k] = pi[k * 64];
    }
    __syncthreads();
    for (int hh = 0; hh < 8; ++hh) {
        const int hl = hg * 8 + hh;
        float ar = 0.f, ai = 0.f;
#pragma unroll
        for (int k4 = 0; k4 < 8; ++k4) {
            const float4 hr4 = *(const float4*)&lhr[hl * 32 + k4 * 4];
            const float4 hi4 = *(const float4*)&lhi[hl * 32 + k4 * 4];
            ar = fmaf(Pr[k4*4+0], hr4.x, fmaf(Pi[k4*4+0], hi4.x, ar));
            ai = fmaf(Pi[k4*4+0], hr4.x, fmaf(-Pr[k4*4+0], hi4.x, ai));
            ar = fmaf(Pr[k4*4+1], hr4.y, fmaf(Pi[k4*4+1], hi4.y, ar));
            ai = fmaf(Pi[k4*4+1], hr4.y, fmaf(-Pr[k4*4+1], hi4.y, ai));
            ar = fmaf(Pr[k4*4+2], hr4.z, fmaf(Pi[k4*4+2], hi4.z, ar));
            ai = fmaf(Pi[k4*4+2], hr4.z, fmaf(-Pr[k4*4+2], hi4.z, ai));
            ar = fmaf(Pr[k4*4+3], hr4.w, fmaf(Pi[k4*4+3], hi4.w, ar));
            ai = fmaf(Pi[k4*4+3], hr4.w, fmaf(-Pr[k4*4+3], hi4.w, ai));
        }
        const int h = hq * 32 + hl;
        const size_t rb = ((size_t)(b * 256 + h) * 64 + o) * 64;
        recO[rb + m]      = f2b(ar);
        recO[rb + 32 + m] = f2b(ai);
    }
}

// K7: MFMA fused final. grid = B*H*4.
__global__ __launch_bounds__(256) void k_final4(
    const float* __restrict__ x,
    const unsigned short* __restrict__ wb_bf,
    const unsigned short* __restrict__ recO,
    const float* __restrict__ mw, const float* __restrict__ mb,
    const float* __restrict__ scw, const float* __restrict__ scb,
    float* __restrict__ out)
{
    constexpr int LD = 72;
    __shared__ __align__(16) unsigned short sWb[64 * LD];
    __shared__ __align__(16) unsigned short sR [64 * LD];
    __shared__ __align__(16) unsigned short sX [64 * LD];
    __shared__ __align__(16) unsigned short sS [64 * LD];
    const int blk = blockIdx.x;
    const int b = blk >> 10, h = (blk >> 2) & 255, wq = blk & 3;
    const int w0 = wq * 64;
    const int t = threadIdx.x;
    const int lane = t & 63, wv = t >> 6;
    const size_t pixbase = (size_t)(b * 256 + h) * 256 + w0;

#pragma unroll
    for (int r = 0; r < 2; ++r) {
        const int idx = r * 256 + t;
        const int px = idx >> 3, f = idx & 7;
        *(uint4*)&sWb[px * LD + f * 8] = *(const uint4*)&wb_bf[(pixbase + px) * 64 + f * 8];
    }
    const size_t recbase = (size_t)(b * 256 + h) * 4096;
#pragma unroll
    for (int r = 0; r < 2; ++r) {
        const int idx = r * 256 + t;
        const int o = idx >> 3, f = idx & 7;
        *(uint4*)&sR[o * LD + f * 8] = *(const uint4*)&recO[recbase + (size_t)o * 64 + f * 8];
    }
#pragma unroll
    for (int r = 0; r < 4; ++r) {
        const int idx = r * 256 + t;
        const int c = idx >> 4, wg = idx & 15;
        const float4 v = *(const float4*)&x[((size_t)(b * 64 + c) * 256 + h) * 256 + w0 + wg * 4];
        sX[(wg * 4 + 0) * LD + c] = f2b(v.x);
        sX[(wg * 4 + 1) * LD + c] = f2b(v.y);
        sX[(wg * 4 + 2) * LD + c] = f2b(v.z);
        sX[(wg * 4 + 3) * LD + c] = f2b(v.w);
    }
    __syncthreads();

    const int arow = lane & 15;
    const int koff = (lane >> 4) * 8;
    const f32x4 zero = {0.f, 0.f, 0.f, 0.f};

    f32x4 accA[4] = {zero, zero, zero, zero};
#pragma unroll
    for (int kc = 0; kc < 2; ++kc) {
        const bf16x8 a = *(const bf16x8*)&sR[(16 * wv + arow) * LD + kc * 32 + koff];
#pragma unroll
        for (int nt = 0; nt < 4; ++nt) {
            const bf16x8 bb = *(const bf16x8*)&sWb[(nt * 16 + arow) * LD + kc * 32 + koff];
            accA[nt] = __builtin_amdgcn_mfma_f32_16x16x32_bf16(a, bb, accA[nt], 0, 0, 0);
        }
    }
    __syncthreads();

    const int crow = 16 * wv + (lane >> 4) * 4;
#pragma unroll
    for (int nt = 0; nt < 4; ++nt) {
        const int px = nt * 16 + arow;
#pragma unroll
        for (int j = 0; j < 4; ++j)
            sS[px * LD + crow + j] = f2b(accA[nt][j] * (1.0f / 65536.0f));
    }
#pragma unroll
    for (int r = 0; r < 4; ++r) {
        const int idx = r * 256 + t;
        const int o = idx >> 4, cq = idx & 15;
        const float4 v1 = *(const float4*)&mw[o * 64 + cq * 4];
        ushort4 u1;
        u1.x = f2b(v1.x); u1.y = f2b(v1.y); u1.z = f2b(v1.z); u1.w = f2b(v1.w);
        *(ushort4*)&sWb[o * LD + cq * 4] = u1;
        const float4 v2 = *(const float4*)&scw[o * 64 + cq * 4];
        ushort4 u2;
        u2.x = f2b(v2.x); u2.y = f2b(v2.y); u2.z = f2b(v2.z); u2.w = f2b(v2.w);
        *(ushort4*)&sR[o * LD + cq * 4] = u2;
    }
    __syncthreads();

    f32x4 accB[4] = {zero, zero, zero, zero};
    f32x4 accC[4] = {zero, zero, zero, zero};
#pragma unroll
    for (int kc = 0; kc < 2; ++kc) {
        const bf16x8 am = *(const bf16x8*)&sWb[(16 * wv + arow) * LD + kc * 32 + koff];
        const bf16x8 as = *(const bf16x8*)&sR [(16 * wv + arow) * LD + kc * 32 + koff];
#pragma unroll
        for (int nt = 0; nt < 4; ++nt) {
            const bf16x8 bs = *(const bf16x8*)&sS[(nt * 16 + arow) * LD + kc * 32 + koff];
            const bf16x8 bx = *(const bf16x8*)&sX[(nt * 16 + arow) * LD + kc * 32 + koff];
            accB[nt] = __builtin_amdgcn_mfma_f32_16x16x32_bf16(am, bs, accB[nt], 0, 0, 0);
            accC[nt] = __builtin_amdgcn_mfma_f32_16x16x32_bf16(as, bx, accC[nt], 0, 0, 0);
        }
    }

#pragma unroll
    for (int nt = 0; nt < 4; ++nt) {
        const int px = nt * 16 + arow;
#pragma unroll
        for (int j = 0; j < 4; ++j) {
            const int o = crow + j;
            const float y = gelu_f(accB[nt][j] + mb[o]);
            const float z = y + accC[nt][j] + scb[o];
            out[((size_t)(b * 64 + o) * 256 + h) * 256 + w0 + px] = gelu_f(z);
        }
    }
}

extern "C" void kernel_launch(void* const* d_in, const int* in_sizes, int n_in,
                              void* d_out, int out_size, void* d_ws, size_t ws_size,
                              hipStream_t stream) {
    const float* x    = (const float*)d_in[0];
    const float* wW0  = (const float*)d_in[1];
    const float* wb0  = (const float*)d_in[2];
    const float* wW1  = (const float*)d_in[3];
    const float* wb1  = (const float*)d_in[4];
    const float* wW2  = (const float*)d_in[5];
    const float* wb2  = (const float*)d_in[6];
    const float* hW0  = (const float*)d_in[7];
    const float* hb0  = (const float*)d_in[8];
    const float* hW1  = (const float*)d_in[9];
    const float* hb1  = (const float*)d_in[10];
    const float* hW2  = (const float*)d_in[11];
    const float* hb2  = (const float*)d_in[12];
    const float* Wf_re = (const float*)d_in[13];
    const float* Wf_im = (const float*)d_in[14];
    const float* mw   = (const float*)d_in[15];
    const float* mbv  = (const float*)d_in[16];
    const float* scw  = (const float*)d_in[17];
    const float* scb  = (const float*)d_in[18];

    char* base = (char*)d_ws;
    unsigned short* wb_bf = (unsigned short*)(base + 0);            // 33,554,432
    unsigned short* wbT   = (unsigned short*)(base + 33554432);     // 33,554,432
    float* tfwM   = (float*)(base + 67108864);                      // 16,777,216
    unsigned short* hb_bf = (unsigned short*)(base + 83886080);     //  4,194,304
    float* tfhw_p = (float*)(base + 88080384);                      //  8,388,608 (4 parts)
    float* tfhw   = (float*)(base + 96468992);                      //  2,097,152 (re||im)
    float* proc_p = (float*)(base + 98566144);                      //  4,194,304 (2 parts)
    float* procT  = (float*)(base + 102760448);                     //  2,097,152 (re||im)
    unsigned short* recO = (unsigned short*)(base + 104857600);     //  8,388,608
    unsigned short* wT0 = (unsigned short*)(base + 113246208);
    unsigned short* wT1 = (unsigned short*)(base + 113258496);
    unsigned short* wT2 = (unsigned short*)(base + 113266688);
    unsigned short* hT0 = (unsigned short*)(base + 113274880);
    unsigned short* hT1 = (unsigned short*)(base + 113287168);
    unsigned short* hT2 = (unsigned short*)(base + 113295360);

    k_prep<<<1, 256, 0, stream>>>(wW0, wW1, wW2, hW0, hW1, hW2,
                                  wT0, wT1, wT2, hT0, hT1, hT2);
    k_wb_mlp2<<<4096, 256, 0, stream>>>(x, wT0, wb0, wT1, wb1, wT2, wb2, wb_bf, wbT);
    k_tfw2<<<1024, 256, 0, stream>>>(x, wbT, tfwM);
    k_hb_mlp2<<<512, 256, 0, stream>>>(tfwM, hT0, hb0, hT1, hb1, hT2, hb2, hb_bf);
    k_tfhw3<<<1024, 256, 0, stream>>>(tfwM, hb_bf, tfhw_p);
    k_psum<<<1024, 256, 0, stream>>>(tfhw_p, tfhw, 4, 524288);
    k_proc2<<<512, 256, 0, stream>>>(tfhw, Wf_re, Wf_im, proc_p);
    k_psum_procT<<<1024, 256, 0, stream>>>(proc_p, procT);
    k_rec4<<<1024, 256, 0, stream>>>(procT, hb_bf, recO);
    k_final4<<<4096, 256, 0, stream>>>(x, wb_bf, recO, mw, mbv, scw, scb, (float*)d_out);
}

// Round 8
// 195.500 us; speedup vs baseline: 1.4911x; 1.0714x over previous
//
#include <hip/hip_runtime.h>
#include <math.h>

// B=4, C=64, OUT=64, H=256, W=256, M1=32, M2=32, HID=64, COORD=65

typedef __attribute__((ext_vector_type(8))) short bf16x8;
typedef __attribute__((ext_vector_type(4))) float f32x4;

// Fast exact-erf GELU: Abramowitz-Stegun 7.1.26, |eps_erf| <= 1.5e-7.
__device__ __forceinline__ float gelu_f(float v) {
    const float u = v * 0.70710678118654752440f;
    const float xa = fabsf(u);
    const float t = __builtin_amdgcn_rcpf(fmaf(0.3275911f, xa, 1.0f));
    float p = fmaf(1.061405429f, t, -1.453152027f);
    p = fmaf(p, t, 1.421413741f);
    p = fmaf(p, t, -0.284496736f);
    p = fmaf(p, t, 0.254829592f);
    p *= t;
    const float e = __expf(-xa * xa);
    float erfv = fmaf(-p, e, 1.0f);
    erfv = (u < 0.0f) ? -erfv : erfv;
    return 0.5f * v * (1.0f + erfv);
}

__device__ __forceinline__ unsigned short f2b(float f) {
    union { float f; unsigned int u; } v; v.f = f;
    unsigned int u = v.u + 0x7FFFu + ((v.u >> 16) & 1u);   // RNE
    return (unsigned short)(u >> 16);
}
__device__ __forceinline__ float b2f(unsigned short b) {
    union { unsigned int u; float f; } v; v.u = ((unsigned int)b) << 16;
    return v.f;
}

// ---------------------------------------------------------------------------
// Stage x^T into LDS [w_local][c] bf16 via in-register 4x4 butterfly transpose.
// Lanes l, l^16, l^32, l^48 (g = l>>4) exchange float4 loaded at c = cb+g.
// One ushort4 write per thread per round (2-way max bank aliasing).
// ---------------------------------------------------------------------------
__device__ __forceinline__ void stage_xT(const float* __restrict__ x,
    unsigned short* __restrict__ sA, int b, int h, int w0, int t, int LD)
{
    const int lane = t & 63, wv = t >> 6;
    const int g = lane >> 4, wg = lane & 15;
#pragma unroll
    for (int r = 0; r < 4; ++r) {
        const int cb = r * 16 + wv * 4;
        const float4 v = *(const float4*)&x[((size_t)(b * 64 + cb + g) * 256 + h) * 256 + w0 + wg * 4];
        // stage 1: partner g^1 (lane ^ 16)
        const float bx = __shfl_xor(v.x, 16);
        const float by = __shfl_xor(v.y, 16);
        const float bz = __shfl_xor(v.z, 16);
        const float bw = __shfl_xor(v.w, 16);
        float4 s1;
        s1.x = ((g & 1) == 0) ? v.x : by;
        s1.y = ((g & 1) == 0) ? bx  : v.y;
        s1.z = ((g & 1) == 0) ? v.z : bw;
        s1.w = ((g & 1) == 0) ? bz  : v.w;
        // stage 2: partner g^2 (lane ^ 32)
        const float cx = __shfl_xor(s1.x, 32);
        const float cy = __shfl_xor(s1.y, 32);
        const float cz = __shfl_xor(s1.z, 32);
        const float cw = __shfl_xor(s1.w, 32);
        float4 s2;
        s2.x = ((g & 2) == 0) ? s1.x : cz;
        s2.y = ((g & 2) == 0) ? s1.y : cw;
        s2.z = ((g & 2) == 0) ? cx   : s1.z;
        s2.w = ((g & 2) == 0) ? cy   : s1.w;
        ushort4 u;
        u.x = f2b(s2.x); u.y = f2b(s2.y); u.z = f2b(s2.z); u.w = f2b(s2.w);
        *(ushort4*)&sA[(wg * 4 + g) * LD + cb] = u;
    }
}

// ---------------------------------------------------------------------------
// K_prep: transpose + bf16-convert MLP weights. wT[o][k] = W[k][o]. K0 pad->96.
// ---------------------------------------------------------------------------
__global__ void k_prep(const float* __restrict__ wW0, const float* __restrict__ wW1,
                       const float* __restrict__ wW2,
                       const float* __restrict__ hW0, const float* __restrict__ hW1,
                       const float* __restrict__ hW2,
                       unsigned short* __restrict__ wT0, unsigned short* __restrict__ wT1,
                       unsigned short* __restrict__ wT2,
                       unsigned short* __restrict__ hT0, unsigned short* __restrict__ hT1,
                       unsigned short* __restrict__ hT2)
{
    const int t = threadIdx.x;
    for (int idx = t; idx < 64 * 96; idx += 256) {
        const int o = idx / 96, k = idx % 96;
        wT0[idx] = (k < 65) ? f2b(wW0[k * 64 + o]) : (unsigned short)0;
        hT0[idx] = (k < 65) ? f2b(hW0[k * 64 + o]) : (unsigned short)0;
    }
    for (int idx = t; idx < 4096; idx += 256) {
        const int o = idx >> 6, k = idx & 63;
        wT1[idx] = f2b(wW1[k * 64 + o]);
        wT2[idx] = f2b(wW2[k * 64 + o]);
        hT1[idx] = f2b(hW1[k * 64 + o]);
        hT2[idx] = f2b(hW2[k * 64 + o]);
    }
}

// generic partial-sum
__global__ __launch_bounds__(256) void k_psum(const float* __restrict__ src,
                                              float* __restrict__ dst,
                                              int nparts, int part_stride)
{
    const int i = (blockIdx.x * 256 + threadIdx.x) * 4;
    float4 acc = *(const float4*)&src[i];
    for (int p = 1; p < nparts; ++p) {
        const float4 v = *(const float4*)&src[(size_t)p * part_stride + i];
        acc.x += v.x; acc.y += v.y; acc.z += v.z; acc.w += v.w;
    }
    *(float4*)&dst[i] = acc;
}

// psum for proc + repack to procT[((b*32+m)*32+k)*64+o] (re || im at +262144).
__global__ __launch_bounds__(256) void k_psum_procT(const float* __restrict__ src,
                                                    float* __restrict__ dst)
{
    const int idx = blockIdx.x * 256 + threadIdx.x;
    const int o = idx & 63, k = (idx >> 6) & 31, m = (idx >> 11) & 31, b = idx >> 16;
    const size_t in = (size_t)(b * 64 + o) * 1024 + k * 32 + m;
    const float re = src[in] + src[524288 + in];
    const float im = src[262144 + in] + src[524288 + 262144 + in];
    dst[idx] = re;
    dst[262144 + idx] = im;
}

// ---------------------------------------------------------------------------
// MFMA MLP layer
// ---------------------------------------------------------------------------
constexpr int MLD = 104;

template<bool GELU, int NKC>
__device__ __forceinline__ void mfma_layer(
    const unsigned short* __restrict__ sW,
    const unsigned short* __restrict__ sAct,
    unsigned short* __restrict__ dst,
    const float* __restrict__ bias, int lane, int wv)
{
    const int arow = lane & 15;
    const int koff = (lane >> 4) * 8;
    const int crow = 16 * wv + (lane >> 4) * 4;
    const f32x4 zero = {0.f, 0.f, 0.f, 0.f};
    f32x4 acc[4] = {zero, zero, zero, zero};
#pragma unroll
    for (int kc = 0; kc < NKC; ++kc) {
        const bf16x8 a = *(const bf16x8*)&sW[(16 * wv + arow) * MLD + kc * 32 + koff];
#pragma unroll
        for (int nt = 0; nt < 4; ++nt) {
            const bf16x8 b = *(const bf16x8*)&sAct[(nt * 16 + arow) * MLD + kc * 32 + koff];
            acc[nt] = __builtin_amdgcn_mfma_f32_16x16x32_bf16(a, b, acc[nt], 0, 0, 0);
        }
    }
    const float4 bv = *(const float4*)&bias[crow];
#pragma unroll
    for (int nt = 0; nt < 4; ++nt) {
        const int px = nt * 16 + arow;
        float v0 = acc[nt][0] + bv.x;
        float v1 = acc[nt][1] + bv.y;
        float v2 = acc[nt][2] + bv.z;
        float v3 = acc[nt][3] + bv.w;
        if (GELU) { v0 = gelu_f(v0); v1 = gelu_f(v1); v2 = gelu_f(v2); v3 = gelu_f(v3); }
        ushort4 u;
        u.x = f2b(v0); u.y = f2b(v1); u.z = f2b(v2); u.w = f2b(v3);
        *(ushort4*)&dst[px * MLD + crow] = u;
    }
}

__device__ __forceinline__ void stage_wT96(const unsigned short* __restrict__ src,
                                           unsigned short* __restrict__ sW, int t) {
#pragma unroll
    for (int r = 0; r < 3; ++r) {
        const int idx = r * 256 + t;
        const int row = idx / 12, f = idx % 12;
        *(uint4*)&sW[row * MLD + f * 8] = *(const uint4*)&src[row * 96 + f * 8];
    }
}
__device__ __forceinline__ void stage_wT64(const unsigned short* __restrict__ src,
                                           unsigned short* __restrict__ sW, int t) {
#pragma unroll
    for (int r = 0; r < 2; ++r) {
        const int idx = r * 256 + t;
        const int row = idx >> 3, f = idx & 7;
        *(uint4*)&sW[row * MLD + f * 8] = *(const uint4*)&src[row * 64 + f * 8];
    }
}

// K1: wb basis via MFMA. grid = B*H*4. wb_bf[pix][64] + wbT[b,h][o][w] (reg stores).
__global__ __launch_bounds__(256) void k_wb_mlp2(
    const float* __restrict__ x,
    const unsigned short* __restrict__ wT0, const float* __restrict__ b0,
    const unsigned short* __restrict__ wT1, const float* __restrict__ b1,
    const unsigned short* __restrict__ wT2, const float* __restrict__ b2,
    unsigned short* __restrict__ wb_bf, unsigned short* __restrict__ wbT)
{
    __shared__ __align__(16) unsigned short sA[64 * MLD];
    __shared__ __align__(16) unsigned short sB[64 * MLD];
    __shared__ __align__(16) unsigned short sW[64 * MLD];
    const int blk = blockIdx.x;
    const int b = blk >> 10, h = (blk >> 2) & 255, wq = blk & 3;
    const int w0 = wq * 64;
    const int t = threadIdx.x;
    const int lane = t & 63, wv = t >> 6;

    stage_xT(x, sA, b, h, w0, t, MLD);
    if (t < 64) {
        const uint4 z = {0, 0, 0, 0};
        *(uint4*)&sA[t * MLD + 64] = z;
        *(uint4*)&sA[t * MLD + 72] = z;
        *(uint4*)&sA[t * MLD + 80] = z;
        *(uint4*)&sA[t * MLD + 88] = z;
        sA[t * MLD + 64] = f2b((float)(w0 + t) * (2.0f / 255.0f) - 1.0f);
    }
    stage_wT96(wT0, sW, t);
    __syncthreads();
    mfma_layer<true, 3>(sW, sA, sB, b0, lane, wv);
    __syncthreads();
    stage_wT64(wT1, sW, t);
    __syncthreads();
    mfma_layer<true, 2>(sW, sB, sA, b1, lane, wv);
    __syncthreads();
    stage_wT64(wT2, sW, t);
    __syncthreads();
    // layer 3 inline: write sB (for wb_bf) + wbT directly from registers
    {
        const int arow = lane & 15;
        const int koff = (lane >> 4) * 8;
        const int crow = 16 * wv + (lane >> 4) * 4;
        const f32x4 zero = {0.f, 0.f, 0.f, 0.f};
        f32x4 acc[4] = {zero, zero, zero, zero};
#pragma unroll
        for (int kc = 0; kc < 2; ++kc) {
            const bf16x8 a = *(const bf16x8*)&sW[(16 * wv + arow) * MLD + kc * 32 + koff];
#pragma unroll
            for (int nt = 0; nt < 4; ++nt) {
                const bf16x8 bb = *(const bf16x8*)&sA[(nt * 16 + arow) * MLD + kc * 32 + koff];
                acc[nt] = __builtin_amdgcn_mfma_f32_16x16x32_bf16(a, bb, acc[nt], 0, 0, 0);
            }
        }
        const float4 bv = *(const float4*)&b2[crow];
        const size_t tb2 = (size_t)(b * 256 + h) * 16384;
#pragma unroll
        for (int nt = 0; nt < 4; ++nt) {
            const int px = nt * 16 + arow;
            ushort4 u;
            u.x = f2b(acc[nt][0] + bv.x);
            u.y = f2b(acc[nt][1] + bv.y);
            u.z = f2b(acc[nt][2] + bv.z);
            u.w = f2b(acc[nt][3] + bv.w);
            *(ushort4*)&sB[px * MLD + crow] = u;
            wbT[tb2 + (size_t)(crow + 0) * 256 + w0 + px] = u.x;
            wbT[tb2 + (size_t)(crow + 1) * 256 + w0 + px] = u.y;
            wbT[tb2 + (size_t)(crow + 2) * 256 + w0 + px] = u.z;
            wbT[tb2 + (size_t)(crow + 3) * 256 + w0 + px] = u.w;
        }
    }
    __syncthreads();

    const size_t pixbase = (size_t)(b * 256 + h) * 256 + w0;
#pragma unroll
    for (int r = 0; r < 2; ++r) {
        const int idx = r * 256 + t;
        const int px = idx >> 3, f = idx & 7;
        *(uint4*)&wb_bf[(pixbase + px) * 64 + f * 8] = *(const uint4*)&sB[px * MLD + f * 8];
    }
}

// K2: tfw via MFMA. grid = B*H (1024).
__global__ __launch_bounds__(256) void k_tfw2(
    const float* __restrict__ x,
    const unsigned short* __restrict__ wbT,
    float* __restrict__ tfwM)
{
    constexpr int TLD = 264;
    __shared__ __align__(16) unsigned short sW[64 * TLD];
    __shared__ __align__(16) unsigned short sX[64 * TLD];
    const int bh = blockIdx.x;
    const int b = bh >> 8, h = bh & 255;
    const int t = threadIdx.x;
    const int lane = t & 63, wv = t >> 6;

    const size_t wtb = (size_t)bh * 16384;
#pragma unroll
    for (int r = 0; r < 8; ++r) {
        const int idx = r * 256 + t;
        const int row = idx >> 5, f = idx & 31;
        *(uint4*)&sW[row * TLD + f * 8] = *(const uint4*)&wbT[wtb + (size_t)row * 256 + f * 8];
    }
#pragma unroll
    for (int r = 0; r < 16; ++r) {
        const int idx = r * 256 + t;
        const int c = idx >> 6, f = idx & 63;
        const float4 v = *(const float4*)&x[((size_t)(b * 64 + c) * 256 + h) * 256 + f * 4];
        ushort4 u; u.x = f2b(v.x); u.y = f2b(v.y); u.z = f2b(v.z); u.w = f2b(v.w);
        *(ushort4*)&sX[c * TLD + f * 4] = u;
    }
    __syncthreads();

    const int arow = lane & 15;
    const int koff = (lane >> 4) * 8;
    const f32x4 zero = {0.f, 0.f, 0.f, 0.f};
    f32x4 acc[4] = {zero, zero, zero, zero};
#pragma unroll
    for (int kc = 0; kc < 8; ++kc) {
        const bf16x8 a = *(const bf16x8*)&sW[(16 * wv + arow) * TLD + kc * 32 + koff];
#pragma unroll
        for (int nt = 0; nt < 4; ++nt) {
            const bf16x8 bb = *(const bf16x8*)&sX[(nt * 16 + arow) * TLD + kc * 32 + koff];
            acc[nt] = __builtin_amdgcn_mfma_f32_16x16x32_bf16(a, bb, acc[nt], 0, 0, 0);
        }
    }
    __syncthreads();
    float* sF = (float*)sW;
    const int crow = 16 * wv + (lane >> 4) * 4;
#pragma unroll
    for (int nt = 0; nt < 4; ++nt) {
        const int c = nt * 16 + arow;
#pragma unroll
        for (int j = 0; j < 4; ++j)
            sF[(crow + j) * 68 + c] = acc[nt][j];
    }
    __syncthreads();
#pragma unroll
    for (int r = 0; r < 4; ++r) {
        const int idx = r * 256 + t;
        const int m = idx >> 5, g = idx & 31;
        float4 v;
        v.x = sF[m * 68 + g * 2];
        v.y = sF[(m + 32) * 68 + g * 2];
        v.z = sF[m * 68 + g * 2 + 1];
        v.w = sF[(m + 32) * 68 + g * 2 + 1];
        *(float4*)&tfwM[((size_t)(b * 32 + m) * 256 + h) * 128 + g * 4] = v;
    }
}

// K3: hb basis via MFMA. grid = B*M2*4.
__global__ __launch_bounds__(256) void k_hb_mlp2(
    const float* __restrict__ tfwM,
    const unsigned short* __restrict__ hT0, const float* __restrict__ b0,
    const unsigned short* __restrict__ hT1, const float* __restrict__ b1,
    const unsigned short* __restrict__ hT2, const float* __restrict__ b2,
    unsigned short* __restrict__ hb_bf)
{
    __shared__ __align__(16) unsigned short sA[64 * MLD];
    __shared__ __align__(16) unsigned short sB[64 * MLD];
    __shared__ __align__(16) unsigned short sW[64 * MLD];
    const int blk = blockIdx.x;
    const int bm = blk >> 2, hq = blk & 3;
    const int h0 = hq * 64;
    const int t = threadIdx.x;
    const int lane = t & 63, wv = t >> 6;

#pragma unroll
    for (int r = 0; r < 4; ++r) {
        const int idx = r * 256 + t;
        const int p = idx >> 4, f = idx & 15;
        const float* src = &tfwM[(size_t)(bm * 256 + h0 + p) * 128 + f * 8];
        const float4 u0 = *(const float4*)&src[0];
        const float4 u1 = *(const float4*)&src[4];
        ushort4 u;
        u.x = f2b(u0.x); u.y = f2b(u0.z); u.z = f2b(u1.x); u.w = f2b(u1.z);
        *(ushort4*)&sA[p * MLD + f * 4] = u;
    }
    if (t < 64) {
        const uint4 z = {0, 0, 0, 0};
        *(uint4*)&sA[t * MLD + 64] = z;
        *(uint4*)&sA[t * MLD + 72] = z;
        *(uint4*)&sA[t * MLD + 80] = z;
        *(uint4*)&sA[t * MLD + 88] = z;
        sA[t * MLD + 64] = f2b((float)(h0 + t) * (2.0f / 255.0f) - 1.0f);
    }
    stage_wT96(hT0, sW, t);
    __syncthreads();
    mfma_layer<true, 3>(sW, sA, sB, b0, lane, wv);
    __syncthreads();
    stage_wT64(hT1, sW, t);
    __syncthreads();
    mfma_layer<true, 2>(sW, sB, sA, b1, lane, wv);
    __syncthreads();
    stage_wT64(hT2, sW, t);
    __syncthreads();
    mfma_layer<false, 2>(sW, sA, sB, b2, lane, wv);
    __syncthreads();

    const size_t pixbase = (size_t)bm * 256 + h0;
#pragma unroll
    for (int r = 0; r < 2; ++r) {
        const int idx = r * 256 + t;
        const int px = idx >> 3, f = idx & 7;
        *(uint4*)&hb_bf[(pixbase + px) * 64 + f * 8] = *(const uint4*)&sB[px * MLD + f * 8];
    }
}

// K4: tfhw partials. grid = 1024: (bm, chalf, hq).
__global__ __launch_bounds__(256) void k_tfhw3(
    const float* __restrict__ tfwM,
    const unsigned short* __restrict__ hb_bf,
    float* __restrict__ tfhw_p)
{
    __shared__ float hr[64 * 32];
    __shared__ float hi2[64 * 32];
    __shared__ float slab[32 * 64];
    const int blk = blockIdx.x;
    const int bm = blk >> 3, chalf = (blk >> 2) & 1, hq = blk & 3;
    const int b = bm >> 5, m = bm & 31;
    const int t = threadIdx.x;
#pragma unroll
    for (int r = 0; r < 2; ++r) {
        const int q = r * 256 + t;
        const int hl = q >> 3, f = q & 7;
        const uint4 raw = *(const uint4*)&hb_bf[((size_t)bm * 256 + hq * 64 + hl) * 64 + f * 8];
        const unsigned short* us = (const unsigned short*)&raw;
        float v[8];
#pragma unroll
        for (int j = 0; j < 8; ++j) v[j] = b2f(us[j]);
        float* dst = (f < 4) ? &hr[hl * 32 + f * 8] : &hi2[hl * 32 + (f - 4) * 8];
        float4 lo; lo.x = v[0]; lo.y = v[1]; lo.z = v[2]; lo.w = v[3];
        float4 hi; hi.x = v[4]; hi.y = v[5]; hi.z = v[6]; hi.w = v[7];
        *(float4*)&dst[0] = lo;
        *(float4*)&dst[4] = hi;
    }
    const int k = t & 31, cq = t >> 5;
    float accr[4] = {0.f, 0.f, 0.f, 0.f}, acci[4] = {0.f, 0.f, 0.f, 0.f};
    const size_t tbase = (size_t)bm * 32768;
    for (int ht = 0; ht < 2; ++ht) {
        __syncthreads();
#pragma unroll
        for (int r = 0; r < 2; ++r) {
            const int q = r * 256 + t;
            const int hl = q >> 3, f = q & 7;
            *(float4*)&slab[hl * 64 + f * 4] =
                *(const float4*)&tfwM[tbase + (size_t)(hq * 64 + ht * 32 + hl) * 128 + chalf * 64 + f * 4];
        }
        __syncthreads();
#pragma unroll 8
        for (int hl = 0; hl < 32; ++hl) {
            const float hrv = hr[(ht * 32 + hl) * 32 + k];
            const float hiv = hi2[(ht * 32 + hl) * 32 + k];
            const float4 u0 = *(const float4*)&slab[hl * 64 + cq * 8];
            const float4 u1 = *(const float4*)&slab[hl * 64 + cq * 8 + 4];
            accr[0] = fmaf(u0.x, hrv, fmaf(-u0.y, hiv, accr[0]));
            acci[0] = fmaf(u0.x, hiv, fmaf( u0.y, hrv, acci[0]));
            accr[1] = fmaf(u0.z, hrv, fmaf(-u0.w, hiv, accr[1]));
            acci[1] = fmaf(u0.z, hiv, fmaf( u0.w, hrv, acci[1]));
            accr[2] = fmaf(u1.x, hrv, fmaf(-u1.y, hiv, accr[2]));
            acci[2] = fmaf(u1.x, hiv, fmaf( u1.y, hrv, acci[2]));
            accr[3] = fmaf(u1.z, hrv, fmaf(-u1.w, hiv, accr[3]));
            acci[3] = fmaf(u1.z, hiv, fmaf( u1.w, hrv, acci[3]));
        }
    }
    float* tp = tfhw_p + (size_t)hq * 524288;
#pragma unroll
    for (int i = 0; i < 4; ++i) {
        const int c = chalf * 32 + cq * 4 + i;
        const size_t po = ((size_t)(b * 64 + c) * 32 + k) * 32 + m;
        tp[po] = accr[i];
        tp[262144 + po] = acci[i];
    }
}

// K5: proc partials. grid = 512: (o, kq, chalf).
__global__ __launch_bounds__(256) void k_proc2(
    const float* __restrict__ tfhw,
    const float* __restrict__ Wf_re, const float* __restrict__ Wf_im,
    float* __restrict__ proc_p)
{
    const int blk = blockIdx.x;
    const int o = blk >> 3, kq = (blk >> 1) & 3, chalf = blk & 1;
    const int t = threadIdx.x;
    const int mo = kq * 256 + t;
    const float* tre = tfhw;
    const float* tim = tfhw + 262144;
    float accr[4] = {0.f, 0.f, 0.f, 0.f}, acci[4] = {0.f, 0.f, 0.f, 0.f};
    for (int cc = 0; cc < 32; ++cc) {
        const int c = chalf * 32 + cc;
        const float wfr = Wf_re[(size_t)(c * 64 + o) * 1024 + mo];
        const float wfi = Wf_im[(size_t)(c * 64 + o) * 1024 + mo];
#pragma unroll
        for (int bb = 0; bb < 4; ++bb) {
            const float tr = tre[(size_t)(bb * 64 + c) * 1024 + mo];
            const float ti = tim[(size_t)(bb * 64 + c) * 1024 + mo];
            accr[bb] = fmaf(tr, wfr, fmaf(-ti, wfi, accr[bb]));
            acci[bb] = fmaf(tr, wfi, fmaf(ti, wfr, acci[bb]));
        }
    }
    float* pp = proc_p + (size_t)chalf * 524288;
#pragma unroll
    for (int bb = 0; bb < 4; ++bb) {
        pp[(size_t)(bb * 64 + o) * 1024 + mo] = accr[bb];
        pp[262144 + (size_t)(bb * 64 + o) * 1024 + mo] = acci[bb];
    }
}

// K6: recO bf16. grid = 1024: (bm, hq8). Coalesced procT reads.
__global__ __launch_bounds__(256) void k_rec4(
    const float* __restrict__ procT,
    const unsigned short* __restrict__ hb_bf,
    unsigned short* __restrict__ recO)
{
    __shared__ float lhr[32 * 32];
    __shared__ float lhi[32 * 32];
    const int blk = blockIdx.x;
    const int bm = blk >> 3, hq = blk & 7;
    const int b = bm >> 5, m = bm & 31;
    const int t = threadIdx.x;
    {
        const int hl = t >> 3, f = t & 7;
        const uint4 raw = *(const uint4*)&hb_bf[((size_t)bm * 256 + hq * 32 + hl) * 64 + f * 8];
        const unsigned short* us = (const unsigned short*)&raw;
        float v[8];
#pragma unroll
        for (int j = 0; j < 8; ++j) v[j] = b2f(us[j]);
        float* dst = (f < 4) ? &lhr[hl * 32 + f * 8] : &lhi[hl * 32 + (f - 4) * 8];
        float4 lo; lo.x = v[0]; lo.y = v[1]; lo.z = v[2]; lo.w = v[3];
        float4 hi; hi.x = v[4]; hi.y = v[5]; hi.z = v[6]; hi.w = v[7];
        *(float4*)&dst[0] = lo;
        *(float4*)&dst[4] = hi;
    }
    const int o = t & 63, hg = t >> 6;
    const float* pr = procT + (size_t)(b * 32 + m) * 2048 + o;
    const float* pi = pr + 262144;
    float Pr[32], Pi[32];
#pragma unroll
    for (int k = 0; k < 32; ++k) {
        Pr[k] = pr[k * 64];
        Pi[k] = pi[k * 64];
    }
    __syncthreads();
    for (int hh = 0; hh < 8; ++hh) {
        const int hl = hg * 8 + hh;
        float ar = 0.f, ai = 0.f;
#pragma unroll
        for (int k4 = 0; k4 < 8; ++k4) {
            const float4 hr4 = *(const float4*)&lhr[hl * 32 + k4 * 4];
            const float4 hi4 = *(const float4*)&lhi[hl * 32 + k4 * 4];
            ar = fmaf(Pr[k4*4+0], hr4.x, fmaf(Pi[k4*4+0], hi4.x, ar));
            ai = fmaf(Pi[k4*4+0], hr4.x, fmaf(-Pr[k4*4+0], hi4.x, ai));
            ar = fmaf(Pr[k4*4+1], hr4.y, fmaf(Pi[k4*4+1], hi4.y, ar));
            ai = fmaf(Pi[k4*4+1], hr4.y, fmaf(-Pr[k4*4+1], hi4.y, ai));
            ar = fmaf(Pr[k4*4+2], hr4.z, fmaf(Pi[k4*4+2], hi4.z, ar));
            ai = fmaf(Pi[k4*4+2], hr4.z, fmaf(-Pr[k4*4+2], hi4.z, ai));
            ar = fmaf(Pr[k4*4+3], hr4.w, fmaf(Pi[k4*4+3], hi4.w, ar));
            ai = fmaf(Pi[k4*4+3], hr4.w, fmaf(-Pr[k4*4+3], hi4.w, ai));
        }
        const int h = hq * 32 + hl;
        const size_t rb = ((size_t)(b * 256 + h) * 64 + o) * 64;
        recO[rb + m]      = f2b(ar);
        recO[rb + 32 + m] = f2b(ai);
    }
}

// K7: MFMA fused final. grid = B*H*4.
__global__ __launch_bounds__(256) void k_final4(
    const float* __restrict__ x,
    const unsigned short* __restrict__ wb_bf,
    const unsigned short* __restrict__ recO,
    const float* __restrict__ mw, const float* __restrict__ mb,
    const float* __restrict__ scw, const float* __restrict__ scb,
    float* __restrict__ out)
{
    constexpr int LD = 72;
    __shared__ __align__(16) unsigned short sWb[64 * LD];
    __shared__ __align__(16) unsigned short sR [64 * LD];
    __shared__ __align__(16) unsigned short sX [64 * LD];
    __shared__ __align__(16) unsigned short sS [64 * LD];
    const int blk = blockIdx.x;
    const int b = blk >> 10, h = (blk >> 2) & 255, wq = blk & 3;
    const int w0 = wq * 64;
    const int t = threadIdx.x;
    const int lane = t & 63, wv = t >> 6;
    const size_t pixbase = (size_t)(b * 256 + h) * 256 + w0;

#pragma unroll
    for (int r = 0; r < 2; ++r) {
        const int idx = r * 256 + t;
        const int px = idx >> 3, f = idx & 7;
        *(uint4*)&sWb[px * LD + f * 8] = *(const uint4*)&wb_bf[(pixbase + px) * 64 + f * 8];
    }
    const size_t recbase = (size_t)(b * 256 + h) * 4096;
#pragma unroll
    for (int r = 0; r < 2; ++r) {
        const int idx = r * 256 + t;
        const int o = idx >> 3, f = idx & 7;
        *(uint4*)&sR[o * LD + f * 8] = *(const uint4*)&recO[recbase + (size_t)o * 64 + f * 8];
    }
    stage_xT(x, sX, b, h, w0, t, LD);
    __syncthreads();

    const int arow = lane & 15;
    const int koff = (lane >> 4) * 8;
    const f32x4 zero = {0.f, 0.f, 0.f, 0.f};

    f32x4 accA[4] = {zero, zero, zero, zero};
#pragma unroll
    for (int kc = 0; kc < 2; ++kc) {
        const bf16x8 a = *(const bf16x8*)&sR[(16 * wv + arow) * LD + kc * 32 + koff];
#pragma unroll
        for (int nt = 0; nt < 4; ++nt) {
            const bf16x8 bb = *(const bf16x8*)&sWb[(nt * 16 + arow) * LD + kc * 32 + koff];
            accA[nt] = __builtin_amdgcn_mfma_f32_16x16x32_bf16(a, bb, accA[nt], 0, 0, 0);
        }
    }
    __syncthreads();

    const int crow = 16 * wv + (lane >> 4) * 4;
#pragma unroll
    for (int nt = 0; nt < 4; ++nt) {
        const int px = nt * 16 + arow;
#pragma unroll
        for (int j = 0; j < 4; ++j)
            sS[px * LD + crow + j] = f2b(accA[nt][j] * (1.0f / 65536.0f));
    }
#pragma unroll
    for (int r = 0; r < 4; ++r) {
        const int idx = r * 256 + t;
        const int o = idx >> 4, cq = idx & 15;
        const float4 v1 = *(const float4*)&mw[o * 64 + cq * 4];
        ushort4 u1;
        u1.x = f2b(v1.x); u1.y = f2b(v1.y); u1.z = f2b(v1.z); u1.w = f2b(v1.w);
        *(ushort4*)&sWb[o * LD + cq * 4] = u1;
        const float4 v2 = *(const float4*)&scw[o * 64 + cq * 4];
        ushort4 u2;
        u2.x = f2b(v2.x); u2.y = f2b(v2.y); u2.z = f2b(v2.z); u2.w = f2b(v2.w);
        *(ushort4*)&sR[o * LD + cq * 4] = u2;
    }
    __syncthreads();

    f32x4 accB[4] = {zero, zero, zero, zero};
    f32x4 accC[4] = {zero, zero, zero, zero};
#pragma unroll
    for (int kc = 0; kc < 2; ++kc) {
        const bf16x8 am = *(const bf16x8*)&sWb[(16 * wv + arow) * LD + kc * 32 + koff];
        const bf16x8 as = *(const bf16x8*)&sR [(16 * wv + arow) * LD + kc * 32 + koff];
#pragma unroll
        for (int nt = 0; nt < 4; ++nt) {
            const bf16x8 bs = *(const bf16x8*)&sS[(nt * 16 + arow) * LD + kc * 32 + koff];
            const bf16x8 bx = *(const bf16x8*)&sX[(nt * 16 + arow) * LD + kc * 32 + koff];
            accB[nt] = __builtin_amdgcn_mfma_f32_16x16x32_bf16(am, bs, accB[nt], 0, 0, 0);
            accC[nt] = __builtin_amdgcn_mfma_f32_16x16x32_bf16(as, bx, accC[nt], 0, 0, 0);
        }
    }

#pragma unroll
    for (int nt = 0; nt < 4; ++nt) {
        const int px = nt * 16 + arow;
#pragma unroll
        for (int j = 0; j < 4; ++j) {
            const int o = crow + j;
            const float y = gelu_f(accB[nt][j] + mb[o]);
            const float z = y + accC[nt][j] + scb[o];
            out[((size_t)(b * 64 + o) * 256 + h) * 256 + w0 + px] = gelu_f(z);
        }
    }
}

extern "C" void kernel_launch(void* const* d_in, const int* in_sizes, int n_in,
                              void* d_out, int out_size, void* d_ws, size_t ws_size,
                              hipStream_t stream) {
    const float* x    = (const float*)d_in[0];
    const float* wW0  = (const float*)d_in[1];
    const float* wb0  = (const float*)d_in[2];
    const float* wW1  = (const float*)d_in[3];
    const float* wb1  = (const float*)d_in[4];
    const float* wW2  = (const float*)d_in[5];
    const float* wb2  = (const float*)d_in[6];
    const float* hW0  = (const float*)d_in[7];
    const float* hb0  = (const float*)d_in[8];
    const float* hW1  = (const float*)d_in[9];
    const float* hb1  = (const float*)d_in[10];
    const float* hW2  = (const float*)d_in[11];
    const float* hb2  = (const float*)d_in[12];
    const float* Wf_re = (const float*)d_in[13];
    const float* Wf_im = (const float*)d_in[14];
    const float* mw   = (const float*)d_in[15];
    const float* mbv  = (const float*)d_in[16];
    const float* scw  = (const float*)d_in[17];
    const float* scb  = (const float*)d_in[18];

    char* base = (char*)d_ws;
    unsigned short* wb_bf = (unsigned short*)(base + 0);            // 33,554,432
    unsigned short* wbT   = (unsigned short*)(base + 33554432);     // 33,554,432
    float* tfwM   = (float*)(base + 67108864);                      // 16,777,216
    unsigned short* hb_bf = (unsigned short*)(base + 83886080);     //  4,194,304
    float* tfhw_p = (float*)(base + 88080384);                      //  8,388,608 (4 parts)
    float* tfhw   = (float*)(base + 96468992);                      //  2,097,152 (re||im)
    float* proc_p = (float*)(base + 98566144);                      //  4,194,304 (2 parts)
    float* procT  = (float*)(base + 102760448);                     //  2,097,152 (re||im)
    unsigned short* recO = (unsigned short*)(base + 104857600);     //  8,388,608
    unsigned short* wT0 = (unsigned short*)(base + 113246208);
    unsigned short* wT1 = (unsigned short*)(base + 113258496);
    unsigned short* wT2 = (unsigned short*)(base + 113266688);
    unsigned short* hT0 = (unsigned short*)(base + 113274880);
    unsigned short* hT1 = (unsigned short*)(base + 113287168);
    unsigned short* hT2 = (unsigned short*)(base + 113295360);

    k_prep<<<1, 256, 0, stream>>>(wW0, wW1, wW2, hW0, hW1, hW2,
                                  wT0, wT1, wT2, hT0, hT1, hT2);
    k_wb_mlp2<<<4096, 256, 0, stream>>>(x, wT0, wb0, wT1, wb1, wT2, wb2, wb_bf, wbT);
    k_tfw2<<<1024, 256, 0, stream>>>(x, wbT, tfwM);
    k_hb_mlp2<<<512, 256, 0, stream>>>(tfwM, hT0, hb0, hT1, hb1, hT2, hb2, hb_bf);
    k_tfhw3<<<1024, 256, 0, stream>>>(tfwM, hb_bf, tfhw_p);
    k_psum<<<1024, 256, 0, stream>>>(tfhw_p, tfhw, 4, 524288);
    k_proc2<<<512, 256, 0, stream>>>(tfhw, Wf_re, Wf_im, proc_p);
    k_psum_procT<<<1024, 256, 0, stream>>>(proc_p, procT);
    k_rec4<<<1024, 256, 0, stream>>>(procT, hb_bf, recO);
    k_final4<<<4096, 256, 0, stream>>>(x, wb_bf, recO, mw, mbv, scw, scb, (float*)d_out);
}

// Round 9
// 186.490 us; speedup vs baseline: 1.5631x; 1.0483x over previous
//
#include <hip/hip_runtime.h>
#include <math.h>

// B=4, C=64, OUT=64, H=256, W=256, M1=32, M2=32, HID=64, COORD=65

typedef __attribute__((ext_vector_type(8))) short bf16x8;
typedef __attribute__((ext_vector_type(4))) float f32x4;

// Fast exact-erf GELU: Abramowitz-Stegun 7.1.26, |eps_erf| <= 1.5e-7.
__device__ __forceinline__ float gelu_f(float v) {
    const float u = v * 0.70710678118654752440f;
    const float xa = fabsf(u);
    const float t = __builtin_amdgcn_rcpf(fmaf(0.3275911f, xa, 1.0f));
    float p = fmaf(1.061405429f, t, -1.453152027f);
    p = fmaf(p, t, 1.421413741f);
    p = fmaf(p, t, -0.284496736f);
    p = fmaf(p, t, 0.254829592f);
    p *= t;
    const float e = __expf(-xa * xa);
    float erfv = fmaf(-p, e, 1.0f);
    erfv = (u < 0.0f) ? -erfv : erfv;
    return 0.5f * v * (1.0f + erfv);
}

__device__ __forceinline__ unsigned short f2b(float f) {
    union { float f; unsigned int u; } v; v.f = f;
    unsigned int u = v.u + 0x7FFFu + ((v.u >> 16) & 1u);   // RNE
    return (unsigned short)(u >> 16);
}
__device__ __forceinline__ float b2f(unsigned short b) {
    union { unsigned int u; float f; } v; v.u = ((unsigned int)b) << 16;
    return v.f;
}

constexpr int MLD = 104;   // MLP tile row stride (ushort), rows 16B-aligned
constexpr int XLD = 72;    // x-row / wbT-tile row stride (ushort)

// ---------------------------------------------------------------------------
// 4x4 butterfly transpose within 4-lane clusters (lane^1, lane^2).
// Lane l loads x[c = cb+(l&3)][w0 + (l>>2)*4 ..+3]; ends holding x^T row
// (w_local = l), cols cb..cb+3. Writes: lanes 0..63 -> rows 0..63 (2-way max).
// ---------------------------------------------------------------------------
__device__ __forceinline__ ushort4 butterfly_xT(const float4 v, int q) {
    const float bx = __shfl_xor(v.x, 1);
    const float by = __shfl_xor(v.y, 1);
    const float bz = __shfl_xor(v.z, 1);
    const float bw = __shfl_xor(v.w, 1);
    float4 s1;
    s1.x = ((q & 1) == 0) ? v.x : by;
    s1.y = ((q & 1) == 0) ? bx  : v.y;
    s1.z = ((q & 1) == 0) ? v.z : bw;
    s1.w = ((q & 1) == 0) ? bz  : v.w;
    const float cx = __shfl_xor(s1.x, 2);
    const float cy = __shfl_xor(s1.y, 2);
    const float cz = __shfl_xor(s1.z, 2);
    const float cw = __shfl_xor(s1.w, 2);
    float4 s2;
    s2.x = ((q & 2) == 0) ? s1.x : cz;
    s2.y = ((q & 2) == 0) ? s1.y : cw;
    s2.z = ((q & 2) == 0) ? cx   : s1.z;
    s2.w = ((q & 2) == 0) ? cy   : s1.w;
    ushort4 u;
    u.x = f2b(s2.x); u.y = f2b(s2.y); u.z = f2b(s2.z); u.w = f2b(s2.w);
    return u;
}

__device__ __forceinline__ void stage_xT(const float* __restrict__ x,
    unsigned short* __restrict__ sA, int b, int h, int w0, int t, int LD)
{
    const int lane = t & 63, wv = t >> 6;
    const int q = lane & 3, wg = lane >> 2;
#pragma unroll
    for (int r = 0; r < 4; ++r) {
        const int cb = (r * 4 + wv) * 4;
        const float4 v = *(const float4*)&x[((size_t)(b * 64 + cb + q) * 256 + h) * 256 + w0 + wg * 4];
        const ushort4 u = butterfly_xT(v, q);
        *(ushort4*)&sA[(wg * 4 + q) * LD + cb] = u;
    }
}

// ---------------------------------------------------------------------------
// K_prep: transpose + bf16-convert MLP weights. wT[o][k] = W[k][o]. K0 pad->96.
// ---------------------------------------------------------------------------
__global__ void k_prep(const float* __restrict__ wW0, const float* __restrict__ wW1,
                       const float* __restrict__ wW2,
                       const float* __restrict__ hW0, const float* __restrict__ hW1,
                       const float* __restrict__ hW2,
                       unsigned short* __restrict__ wT0, unsigned short* __restrict__ wT1,
                       unsigned short* __restrict__ wT2,
                       unsigned short* __restrict__ hT0, unsigned short* __restrict__ hT1,
                       unsigned short* __restrict__ hT2)
{
    const int t = threadIdx.x;
    for (int idx = t; idx < 64 * 96; idx += 256) {
        const int o = idx / 96, k = idx % 96;
        wT0[idx] = (k < 65) ? f2b(wW0[k * 64 + o]) : (unsigned short)0;
        hT0[idx] = (k < 65) ? f2b(hW0[k * 64 + o]) : (unsigned short)0;
    }
    for (int idx = t; idx < 4096; idx += 256) {
        const int o = idx >> 6, k = idx & 63;
        wT1[idx] = f2b(wW1[k * 64 + o]);
        wT2[idx] = f2b(wW2[k * 64 + o]);
        hT1[idx] = f2b(hW1[k * 64 + o]);
        hT2[idx] = f2b(hW2[k * 64 + o]);
    }
}

// generic partial-sum
__global__ __launch_bounds__(256) void k_psum(const float* __restrict__ src,
                                              float* __restrict__ dst,
                                              int nparts, int part_stride)
{
    const int i = (blockIdx.x * 256 + threadIdx.x) * 4;
    float4 acc = *(const float4*)&src[i];
    for (int p = 1; p < nparts; ++p) {
        const float4 v = *(const float4*)&src[(size_t)p * part_stride + i];
        acc.x += v.x; acc.y += v.y; acc.z += v.z; acc.w += v.w;
    }
    *(float4*)&dst[i] = acc;
}

// psum for proc + repack to procT[((b*32+m)*32+k)*64+o] (re || im at +262144).
__global__ __launch_bounds__(256) void k_psum_procT(const float* __restrict__ src,
                                                    float* __restrict__ dst)
{
    const int idx = blockIdx.x * 256 + threadIdx.x;
    const int o = idx & 63, k = (idx >> 6) & 31, m = (idx >> 11) & 31, b = idx >> 16;
    const size_t in = (size_t)(b * 64 + o) * 1024 + k * 32 + m;
    const float re = src[in] + src[524288 + in];
    const float im = src[262144 + in] + src[524288 + 262144 + in];
    dst[idx] = re;
    dst[262144 + idx] = im;
}

// ---------------------------------------------------------------------------
// MFMA MLP layer
// ---------------------------------------------------------------------------
template<bool GELU, int NKC>
__device__ __forceinline__ void mfma_layer(
    const unsigned short* __restrict__ sW,
    const unsigned short* __restrict__ sAct,
    unsigned short* __restrict__ dst,
    const float* __restrict__ bias, int lane, int wv)
{
    const int arow = lane & 15;
    const int koff = (lane >> 4) * 8;
    const int crow = 16 * wv + (lane >> 4) * 4;
    const f32x4 zero = {0.f, 0.f, 0.f, 0.f};
    f32x4 acc[4] = {zero, zero, zero, zero};
#pragma unroll
    for (int kc = 0; kc < NKC; ++kc) {
        const bf16x8 a = *(const bf16x8*)&sW[(16 * wv + arow) * MLD + kc * 32 + koff];
#pragma unroll
        for (int nt = 0; nt < 4; ++nt) {
            const bf16x8 b = *(const bf16x8*)&sAct[(nt * 16 + arow) * MLD + kc * 32 + koff];
            acc[nt] = __builtin_amdgcn_mfma_f32_16x16x32_bf16(a, b, acc[nt], 0, 0, 0);
        }
    }
    const float4 bv = *(const float4*)&bias[crow];
#pragma unroll
    for (int nt = 0; nt < 4; ++nt) {
        const int px = nt * 16 + arow;
        float v0 = acc[nt][0] + bv.x;
        float v1 = acc[nt][1] + bv.y;
        float v2 = acc[nt][2] + bv.z;
        float v3 = acc[nt][3] + bv.w;
        if (GELU) { v0 = gelu_f(v0); v1 = gelu_f(v1); v2 = gelu_f(v2); v3 = gelu_f(v3); }
        ushort4 u;
        u.x = f2b(v0); u.y = f2b(v1); u.z = f2b(v2); u.w = f2b(v3);
        *(ushort4*)&dst[px * MLD + crow] = u;
    }
}

__device__ __forceinline__ void stage_wT96(const unsigned short* __restrict__ src,
                                           unsigned short* __restrict__ sW, int t) {
#pragma unroll
    for (int r = 0; r < 3; ++r) {
        const int idx = r * 256 + t;
        const int row = idx / 12, f = idx % 12;
        *(uint4*)&sW[row * MLD + f * 8] = *(const uint4*)&src[row * 96 + f * 8];
    }
}
__device__ __forceinline__ void stage_wT64(const unsigned short* __restrict__ src,
                                           unsigned short* __restrict__ sW, int t) {
#pragma unroll
    for (int r = 0; r < 2; ++r) {
        const int idx = r * 256 + t;
        const int row = idx >> 3, f = idx & 7;
        *(uint4*)&sW[row * MLD + f * 8] = *(const uint4*)&src[row * 64 + f * 8];
    }
}

// ---------------------------------------------------------------------------
// K1+K2 fused: wb basis MLP + tfw transform. grid = B*H (1024), 256 threads.
// Per w-tile (4x64): MLP -> wb_bf write + [o][px] tile; tfw MFMA accumulates
// D[mo][c] = sum_w wb^T[mo][w] * x[c][w] across tiles. Epilogue writes tfwM.
// ---------------------------------------------------------------------------
__global__ __launch_bounds__(256) void k_wbtfw(
    const float* __restrict__ x,
    const unsigned short* __restrict__ wT0, const float* __restrict__ b0,
    const unsigned short* __restrict__ wT1, const float* __restrict__ b1,
    const unsigned short* __restrict__ wT2, const float* __restrict__ b2,
    unsigned short* __restrict__ wb_bf, float* __restrict__ tfwM)
{
    __shared__ __align__(16) unsigned short smem[6656 * 3 + 4608 * 2];  // 58368 B
    unsigned short* sA   = smem;              // [64][MLD] MLP act ping
    unsigned short* sB   = smem + 6656;       // [64][MLD] MLP act pong
    unsigned short* sW   = smem + 13312;      // [64..65][MLD] weights
    unsigned short* sXt  = smem + 19968;      // [64 c][XLD] x rows (tile)
    unsigned short* sWBt = smem + 24576;      // [64 o][XLD] wb^T rows (tile)

    const int bh = blockIdx.x;
    const int b = bh >> 8, h = bh & 255;
    const int t = threadIdx.x;
    const int lane = t & 63, wv = t >> 6;
    const int arow = lane & 15;
    const int koff = (lane >> 4) * 8;
    const int crow = 16 * wv + (lane >> 4) * 4;
    const f32x4 zero = {0.f, 0.f, 0.f, 0.f};

    f32x4 atf[4] = {zero, zero, zero, zero};   // tfw accumulator across tiles

    for (int wq = 0; wq < 4; ++wq) {
        const int w0 = wq * 64;
        __syncthreads();   // protect sA/sXt from prior tile's readers
        // dual-stage x: sXt[c][w] rows + sA[px][c] transposed (butterfly)
        {
            const int q = lane & 3, wg = lane >> 2;
#pragma unroll
            for (int r = 0; r < 4; ++r) {
                const int cb = (r * 4 + wv) * 4;
                const int c = cb + q;
                const float4 v = *(const float4*)&x[((size_t)(b * 64 + c) * 256 + h) * 256 + w0 + wg * 4];
                ushort4 ux;
                ux.x = f2b(v.x); ux.y = f2b(v.y); ux.z = f2b(v.z); ux.w = f2b(v.w);
                *(ushort4*)&sXt[c * XLD + wg * 4] = ux;
                const ushort4 u = butterfly_xT(v, q);
                *(ushort4*)&sA[(wg * 4 + q) * MLD + cb] = u;
            }
        }
        if (t < 64) {
            const uint4 z = {0, 0, 0, 0};
            *(uint4*)&sA[t * MLD + 64] = z;
            *(uint4*)&sA[t * MLD + 72] = z;
            *(uint4*)&sA[t * MLD + 80] = z;
            *(uint4*)&sA[t * MLD + 88] = z;
            sA[t * MLD + 64] = f2b((float)(w0 + t) * (2.0f / 255.0f) - 1.0f);
        }
        stage_wT96(wT0, sW, t);
        __syncthreads();
        mfma_layer<true, 3>(sW, sA, sB, b0, lane, wv);
        __syncthreads();
        stage_wT64(wT1, sW, t);
        __syncthreads();
        mfma_layer<true, 2>(sW, sB, sA, b1, lane, wv);
        __syncthreads();
        stage_wT64(wT2, sW, t);
        __syncthreads();
        // layer 2 inline: regs -> sB [px][o] and sWBt [o][px]
        {
            f32x4 acc[4] = {zero, zero, zero, zero};
#pragma unroll
            for (int kc = 0; kc < 2; ++kc) {
                const bf16x8 a = *(const bf16x8*)&sW[(16 * wv + arow) * MLD + kc * 32 + koff];
#pragma unroll
                for (int nt = 0; nt < 4; ++nt) {
                    const bf16x8 bb = *(const bf16x8*)&sA[(nt * 16 + arow) * MLD + kc * 32 + koff];
                    acc[nt] = __builtin_amdgcn_mfma_f32_16x16x32_bf16(a, bb, acc[nt], 0, 0, 0);
                }
            }
            const float4 bv = *(const float4*)&b2[crow];
#pragma unroll
            for (int nt = 0; nt < 4; ++nt) {
                const int px = nt * 16 + arow;
                ushort4 u;
                u.x = f2b(acc[nt][0] + bv.x);
                u.y = f2b(acc[nt][1] + bv.y);
                u.z = f2b(acc[nt][2] + bv.z);
                u.w = f2b(acc[nt][3] + bv.w);
                *(ushort4*)&sB[px * MLD + crow] = u;
                sWBt[(crow + 0) * XLD + px] = u.x;
                sWBt[(crow + 1) * XLD + px] = u.y;
                sWBt[(crow + 2) * XLD + px] = u.z;
                sWBt[(crow + 3) * XLD + px] = u.w;
            }
        }
        __syncthreads();
        // wb_bf coalesced write + tfw partial MFMA (K=64 of this tile)
        const size_t pixbase = (size_t)(b * 256 + h) * 256 + w0;
#pragma unroll
        for (int r = 0; r < 2; ++r) {
            const int idx = r * 256 + t;
            const int px = idx >> 3, f = idx & 7;
            *(uint4*)&wb_bf[(pixbase + px) * 64 + f * 8] = *(const uint4*)&sB[px * MLD + f * 8];
        }
#pragma unroll
        for (int kc = 0; kc < 2; ++kc) {
            const bf16x8 a = *(const bf16x8*)&sWBt[(16 * wv + arow) * XLD + kc * 32 + koff];
#pragma unroll
            for (int nt = 0; nt < 4; ++nt) {
                const bf16x8 bb = *(const bf16x8*)&sXt[(nt * 16 + arow) * XLD + kc * 32 + koff];
                atf[nt] = __builtin_amdgcn_mfma_f32_16x16x32_bf16(a, bb, atf[nt], 0, 0, 0);
            }
        }
    }

    // epilogue: scatter D[mo][c] -> f32 LDS [mo][68], coalesced tfwM write
    __syncthreads();
    float* sF = (float*)smem;   // 64*68*4 = 17408 B, fits in sA+sB region
#pragma unroll
    for (int nt = 0; nt < 4; ++nt) {
        const int c = nt * 16 + arow;
#pragma unroll
        for (int j = 0; j < 4; ++j)
            sF[(crow + j) * 68 + c] = atf[nt][j];
    }
    __syncthreads();
#pragma unroll
    for (int r = 0; r < 4; ++r) {
        const int idx = r * 256 + t;
        const int m = idx >> 5, g = idx & 31;
        float4 v;
        v.x = sF[m * 68 + g * 2];
        v.y = sF[(m + 32) * 68 + g * 2];
        v.z = sF[m * 68 + g * 2 + 1];
        v.w = sF[(m + 32) * 68 + g * 2 + 1];
        *(float4*)&tfwM[((size_t)(b * 32 + m) * 256 + h) * 128 + g * 4] = v;
    }
}

// K3: hb basis via MFMA. grid = B*M2*4.
__global__ __launch_bounds__(256) void k_hb_mlp2(
    const float* __restrict__ tfwM,
    const unsigned short* __restrict__ hT0, const float* __restrict__ b0,
    const unsigned short* __restrict__ hT1, const float* __restrict__ b1,
    const unsigned short* __restrict__ hT2, const float* __restrict__ b2,
    unsigned short* __restrict__ hb_bf)
{
    __shared__ __align__(16) unsigned short sA[64 * MLD];
    __shared__ __align__(16) unsigned short sB[64 * MLD];
    __shared__ __align__(16) unsigned short sW[65 * MLD];
    const int blk = blockIdx.x;
    const int bm = blk >> 2, hq = blk & 3;
    const int h0 = hq * 64;
    const int t = threadIdx.x;
    const int lane = t & 63, wv = t >> 6;

#pragma unroll
    for (int r = 0; r < 4; ++r) {
        const int idx = r * 256 + t;
        const int p = idx >> 4, f = idx & 15;
        const float* src = &tfwM[(size_t)(bm * 256 + h0 + p) * 128 + f * 8];
        const float4 u0 = *(const float4*)&src[0];
        const float4 u1 = *(const float4*)&src[4];
        ushort4 u;
        u.x = f2b(u0.x); u.y = f2b(u0.z); u.z = f2b(u1.x); u.w = f2b(u1.z);
        *(ushort4*)&sA[p * MLD + f * 4] = u;
    }
    if (t < 64) {
        const uint4 z = {0, 0, 0, 0};
        *(uint4*)&sA[t * MLD + 64] = z;
        *(uint4*)&sA[t * MLD + 72] = z;
        *(uint4*)&sA[t * MLD + 80] = z;
        *(uint4*)&sA[t * MLD + 88] = z;
        sA[t * MLD + 64] = f2b((float)(h0 + t) * (2.0f / 255.0f) - 1.0f);
    }
    stage_wT96(hT0, sW, t);
    __syncthreads();
    mfma_layer<true, 3>(sW, sA, sB, b0, lane, wv);
    __syncthreads();
    stage_wT64(hT1, sW, t);
    __syncthreads();
    mfma_layer<true, 2>(sW, sB, sA, b1, lane, wv);
    __syncthreads();
    stage_wT64(hT2, sW, t);
    __syncthreads();
    mfma_layer<false, 2>(sW, sA, sB, b2, lane, wv);
    __syncthreads();

    const size_t pixbase = (size_t)bm * 256 + h0;
#pragma unroll
    for (int r = 0; r < 2; ++r) {
        const int idx = r * 256 + t;
        const int px = idx >> 3, f = idx & 7;
        *(uint4*)&hb_bf[(pixbase + px) * 64 + f * 8] = *(const uint4*)&sB[px * MLD + f * 8];
    }
}

// K4: tfhw partials. grid = 1024: (bm, chalf, hq).
__global__ __launch_bounds__(256) void k_tfhw3(
    const float* __restrict__ tfwM,
    const unsigned short* __restrict__ hb_bf,
    float* __restrict__ tfhw_p)
{
    __shared__ float hr[64 * 32];
    __shared__ float hi2[64 * 32];
    __shared__ float slab[32 * 64];
    const int blk = blockIdx.x;
    const int bm = blk >> 3, chalf = (blk >> 2) & 1, hq = blk & 3;
    const int b = bm >> 5, m = bm & 31;
    const int t = threadIdx.x;
#pragma unroll
    for (int r = 0; r < 2; ++r) {
        const int q = r * 256 + t;
        const int hl = q >> 3, f = q & 7;
        const uint4 raw = *(const uint4*)&hb_bf[((size_t)bm * 256 + hq * 64 + hl) * 64 + f * 8];
        const unsigned short* us = (const unsigned short*)&raw;
        float v[8];
#pragma unroll
        for (int j = 0; j < 8; ++j) v[j] = b2f(us[j]);
        float* dst = (f < 4) ? &hr[hl * 32 + f * 8] : &hi2[hl * 32 + (f - 4) * 8];
        float4 lo; lo.x = v[0]; lo.y = v[1]; lo.z = v[2]; lo.w = v[3];
        float4 hi; hi.x = v[4]; hi.y = v[5]; hi.z = v[6]; hi.w = v[7];
        *(float4*)&dst[0] = lo;
        *(float4*)&dst[4] = hi;
    }
    const int k = t & 31, cq = t >> 5;
    float accr[4] = {0.f, 0.f, 0.f, 0.f}, acci[4] = {0.f, 0.f, 0.f, 0.f};
    const size_t tbase = (size_t)bm * 32768;
    for (int ht = 0; ht < 2; ++ht) {
        __syncthreads();
#pragma unroll
        for (int r = 0; r < 2; ++r) {
            const int q = r * 256 + t;
            const int hl = q >> 3, f = q & 7;
            *(float4*)&slab[hl * 64 + f * 4] =
                *(const float4*)&tfwM[tbase + (size_t)(hq * 64 + ht * 32 + hl) * 128 + chalf * 64 + f * 4];
        }
        __syncthreads();
#pragma unroll 8
        for (int hl = 0; hl < 32; ++hl) {
            const float hrv = hr[(ht * 32 + hl) * 32 + k];
            const float hiv = hi2[(ht * 32 + hl) * 32 + k];
            const float4 u0 = *(const float4*)&slab[hl * 64 + cq * 8];
            const float4 u1 = *(const float4*)&slab[hl * 64 + cq * 8 + 4];
            accr[0] = fmaf(u0.x, hrv, fmaf(-u0.y, hiv, accr[0]));
            acci[0] = fmaf(u0.x, hiv, fmaf( u0.y, hrv, acci[0]));
            accr[1] = fmaf(u0.z, hrv, fmaf(-u0.w, hiv, accr[1]));
            acci[1] = fmaf(u0.z, hiv, fmaf( u0.w, hrv, acci[1]));
            accr[2] = fmaf(u1.x, hrv, fmaf(-u1.y, hiv, accr[2]));
            acci[2] = fmaf(u1.x, hiv, fmaf( u1.y, hrv, acci[2]));
            accr[3] = fmaf(u1.z, hrv, fmaf(-u1.w, hiv, accr[3]));
            acci[3] = fmaf(u1.z, hiv, fmaf( u1.w, hrv, acci[3]));
        }
    }
    float* tp = tfhw_p + (size_t)hq * 524288;
#pragma unroll
    for (int i = 0; i < 4; ++i) {
        const int c = chalf * 32 + cq * 4 + i;
        const size_t po = ((size_t)(b * 64 + c) * 32 + k) * 32 + m;
        tp[po] = accr[i];
        tp[262144 + po] = acci[i];
    }
}

// K5: proc partials. grid = 512: (o, kq, chalf).
__global__ __launch_bounds__(256) void k_proc2(
    const float* __restrict__ tfhw,
    const float* __restrict__ Wf_re, const float* __restrict__ Wf_im,
    float* __restrict__ proc_p)
{
    const int blk = blockIdx.x;
    const int o = blk >> 3, kq = (blk >> 1) & 3, chalf = blk & 1;
    const int t = threadIdx.x;
    const int mo = kq * 256 + t;
    const float* tre = tfhw;
    const float* tim = tfhw + 262144;
    float accr[4] = {0.f, 0.f, 0.f, 0.f}, acci[4] = {0.f, 0.f, 0.f, 0.f};
    for (int cc = 0; cc < 32; ++cc) {
        const int c = chalf * 32 + cc;
        const float wfr = Wf_re[(size_t)(c * 64 + o) * 1024 + mo];
        const float wfi = Wf_im[(size_t)(c * 64 + o) * 1024 + mo];
#pragma unroll
        for (int bb = 0; bb < 4; ++bb) {
            const float tr = tre[(size_t)(bb * 64 + c) * 1024 + mo];
            const float ti = tim[(size_t)(bb * 64 + c) * 1024 + mo];
            accr[bb] = fmaf(tr, wfr, fmaf(-ti, wfi, accr[bb]));
            acci[bb] = fmaf(tr, wfi, fmaf(ti, wfr, acci[bb]));
        }
    }
    float* pp = proc_p + (size_t)chalf * 524288;
#pragma unroll
    for (int bb = 0; bb < 4; ++bb) {
        pp[(size_t)(bb * 64 + o) * 1024 + mo] = accr[bb];
        pp[262144 + (size_t)(bb * 64 + o) * 1024 + mo] = acci[bb];
    }
}

// K6: recO bf16. grid = 1024: (bm, hq8). Coalesced procT reads.
__global__ __launch_bounds__(256) void k_rec4(
    const float* __restrict__ procT,
    const unsigned short* __restrict__ hb_bf,
    unsigned short* __restrict__ recO)
{
    __shared__ float lhr[32 * 32];
    __shared__ float lhi[32 * 32];
    const int blk = blockIdx.x;
    const int bm = blk >> 3, hq = blk & 7;
    const int b = bm >> 5, m = bm & 31;
    const int t = threadIdx.x;
    {
        const int hl = t >> 3, f = t & 7;
        const uint4 raw = *(const uint4*)&hb_bf[((size_t)bm * 256 + hq * 32 + hl) * 64 + f * 8];
        const unsigned short* us = (const unsigned short*)&raw;
        float v[8];
#pragma unroll
        for (int j = 0; j < 8; ++j) v[j] = b2f(us[j]);
        float* dst = (f < 4) ? &lhr[hl * 32 + f * 8] : &lhi[hl * 32 + (f - 4) * 8];
        float4 lo; lo.x = v[0]; lo.y = v[1]; lo.z = v[2]; lo.w = v[3];
        float4 hi; hi.x = v[4]; hi.y = v[5]; hi.z = v[6]; hi.w = v[7];
        *(float4*)&dst[0] = lo;
        *(float4*)&dst[4] = hi;
    }
    const int o = t & 63, hg = t >> 6;
    const float* pr = procT + (size_t)(b * 32 + m) * 2048 + o;
    const float* pi = pr + 262144;
    float Pr[32], Pi[32];
#pragma unroll
    for (int k = 0; k < 32; ++k) {
        Pr[k] = pr[k * 64];
        Pi[k] = pi[k * 64];
    }
    __syncthreads();
    for (int hh = 0; hh < 8; ++hh) {
        const int hl = hg * 8 + hh;
        float ar = 0.f, ai = 0.f;
#pragma unroll
        for (int k4 = 0; k4 < 8; ++k4) {
            const float4 hr4 = *(const float4*)&lhr[hl * 32 + k4 * 4];
            const float4 hi4 = *(const float4*)&lhi[hl * 32 + k4 * 4];
            ar = fmaf(Pr[k4*4+0], hr4.x, fmaf(Pi[k4*4+0], hi4.x, ar));
            ai = fmaf(Pi[k4*4+0], hr4.x, fmaf(-Pr[k4*4+0], hi4.x, ai));
            ar = fmaf(Pr[k4*4+1], hr4.y, fmaf(Pi[k4*4+1], hi4.y, ar));
            ai = fmaf(Pi[k4*4+1], hr4.y, fmaf(-Pr[k4*4+1], hi4.y, ai));
            ar = fmaf(Pr[k4*4+2], hr4.z, fmaf(Pi[k4*4+2], hi4.z, ar));
            ai = fmaf(Pi[k4*4+2], hr4.z, fmaf(-Pr[k4*4+2], hi4.z, ai));
            ar = fmaf(Pr[k4*4+3], hr4.w, fmaf(Pi[k4*4+3], hi4.w, ar));
            ai = fmaf(Pi[k4*4+3], hr4.w, fmaf(-Pr[k4*4+3], hi4.w, ai));
        }
        const int h = hq * 32 + hl;
        const size_t rb = ((size_t)(b * 256 + h) * 64 + o) * 64;
        recO[rb + m]      = f2b(ar);
        recO[rb + 32 + m] = f2b(ai);
    }
}

// K7: MFMA fused final. grid = B*H*4.
__global__ __launch_bounds__(256) void k_final4(
    const float* __restrict__ x,
    const unsigned short* __restrict__ wb_bf,
    const unsigned short* __restrict__ recO,
    const float* __restrict__ mw, const float* __restrict__ mb,
    const float* __restrict__ scw, const float* __restrict__ scb,
    float* __restrict__ out)
{
    constexpr int LD = 72;
    __shared__ __align__(16) unsigned short sWb[64 * LD];
    __shared__ __align__(16) unsigned short sR [64 * LD];
    __shared__ __align__(16) unsigned short sX [64 * LD];
    __shared__ __align__(16) unsigned short sS [64 * LD];
    const int blk = blockIdx.x;
    const int b = blk >> 10, h = (blk >> 2) & 255, wq = blk & 3;
    const int w0 = wq * 64;
    const int t = threadIdx.x;
    const int lane = t & 63, wv = t >> 6;
    const size_t pixbase = (size_t)(b * 256 + h) * 256 + w0;

#pragma unroll
    for (int r = 0; r < 2; ++r) {
        const int idx = r * 256 + t;
        const int px = idx >> 3, f = idx & 7;
        *(uint4*)&sWb[px * LD + f * 8] = *(const uint4*)&wb_bf[(pixbase + px) * 64 + f * 8];
    }
    const size_t recbase = (size_t)(b * 256 + h) * 4096;
#pragma unroll
    for (int r = 0; r < 2; ++r) {
        const int idx = r * 256 + t;
        const int o = idx >> 3, f = idx & 7;
        *(uint4*)&sR[o * LD + f * 8] = *(const uint4*)&recO[recbase + (size_t)o * 64 + f * 8];
    }
    stage_xT(x, sX, b, h, w0, t, LD);
    __syncthreads();

    const int arow = lane & 15;
    const int koff = (lane >> 4) * 8;
    const f32x4 zero = {0.f, 0.f, 0.f, 0.f};

    f32x4 accA[4] = {zero, zero, zero, zero};
#pragma unroll
    for (int kc = 0; kc < 2; ++kc) {
        const bf16x8 a = *(const bf16x8*)&sR[(16 * wv + arow) * LD + kc * 32 + koff];
#pragma unroll
        for (int nt = 0; nt < 4; ++nt) {
            const bf16x8 bb = *(const bf16x8*)&sWb[(nt * 16 + arow) * LD + kc * 32 + koff];
            accA[nt] = __builtin_amdgcn_mfma_f32_16x16x32_bf16(a, bb, accA[nt], 0, 0, 0);
        }
    }
    __syncthreads();

    const int crow = 16 * wv + (lane >> 4) * 4;
#pragma unroll
    for (int nt = 0; nt < 4; ++nt) {
        const int px = nt * 16 + arow;
#pragma unroll
        for (int j = 0; j < 4; ++j)
            sS[px * LD + crow + j] = f2b(accA[nt][j] * (1.0f / 65536.0f));
    }
#pragma unroll
    for (int r = 0; r < 4; ++r) {
        const int idx = r * 256 + t;
        const int o = idx >> 4, cq = idx & 15;
        const float4 v1 = *(const float4*)&mw[o * 64 + cq * 4];
        ushort4 u1;
        u1.x = f2b(v1.x); u1.y = f2b(v1.y); u1.z = f2b(v1.z); u1.w = f2b(v1.w);
        *(ushort4*)&sWb[o * LD + cq * 4] = u1;
        const float4 v2 = *(const float4*)&scw[o * 64 + cq * 4];
        ushort4 u2;
        u2.x = f2b(v2.x); u2.y = f2b(v2.y); u2.z = f2b(v2.z); u2.w = f2b(v2.w);
        *(ushort4*)&sR[o * LD + cq * 4] = u2;
    }
    __syncthreads();

    f32x4 accB[4] = {zero, zero, zero, zero};
    f32x4 accC[4] = {zero, zero, zero, zero};
#pragma unroll
    for (int kc = 0; kc < 2; ++kc) {
        const bf16x8 am = *(const bf16x8*)&sWb[(16 * wv + arow) * LD + kc * 32 + koff];
        const bf16x8 as = *(const bf16x8*)&sR [(16 * wv + arow) * LD + kc * 32 + koff];
#pragma unroll
        for (int nt = 0; nt < 4; ++nt) {
            const bf16x8 bs = *(const bf16x8*)&sS[(nt * 16 + arow) * LD + kc * 32 + koff];
            const bf16x8 bx = *(const bf16x8*)&sX[(nt * 16 + arow) * LD + kc * 32 + koff];
            accB[nt] = __builtin_amdgcn_mfma_f32_16x16x32_bf16(am, bs, accB[nt], 0, 0, 0);
            accC[nt] = __builtin_amdgcn_mfma_f32_16x16x32_bf16(as, bx, accC[nt], 0, 0, 0);
        }
    }

#pragma unroll
    for (int nt = 0; nt < 4; ++nt) {
        const int px = nt * 16 + arow;
#pragma unroll
        for (int j = 0; j < 4; ++j) {
            const int o = crow + j;
            const float y = gelu_f(accB[nt][j] + mb[o]);
            const float z = y + accC[nt][j] + scb[o];
            out[((size_t)(b * 64 + o) * 256 + h) * 256 + w0 + px] = gelu_f(z);
        }
    }
}

extern "C" void kernel_launch(void* const* d_in, const int* in_sizes, int n_in,
                              void* d_out, int out_size, void* d_ws, size_t ws_size,
                              hipStream_t stream) {
    const float* x    = (const float*)d_in[0];
    const float* wW0  = (const float*)d_in[1];
    const float* wb0  = (const float*)d_in[2];
    const float* wW1  = (const float*)d_in[3];
    const float* wb1  = (const float*)d_in[4];
    const float* wW2  = (const float*)d_in[5];
    const float* wb2  = (const float*)d_in[6];
    const float* hW0  = (const float*)d_in[7];
    const float* hb0  = (const float*)d_in[8];
    const float* hW1  = (const float*)d_in[9];
    const float* hb1  = (const float*)d_in[10];
    const float* hW2  = (const float*)d_in[11];
    const float* hb2  = (const float*)d_in[12];
    const float* Wf_re = (const float*)d_in[13];
    const float* Wf_im = (const float*)d_in[14];
    const float* mw   = (const float*)d_in[15];
    const float* mbv  = (const float*)d_in[16];
    const float* scw  = (const float*)d_in[17];
    const float* scb  = (const float*)d_in[18];

    char* base = (char*)d_ws;
    unsigned short* wb_bf = (unsigned short*)(base + 0);            // 33,554,432
    float* tfwM   = (float*)(base + 33554432);                      // 16,777,216
    unsigned short* hb_bf = (unsigned short*)(base + 50331648);     //  4,194,304
    float* tfhw_p = (float*)(base + 54525952);                      //  8,388,608 (4 parts)
    float* tfhw   = (float*)(base + 62914560);                      //  2,097,152 (re||im)
    float* proc_p = (float*)(base + 65011712);                      //  4,194,304 (2 parts)
    float* procT  = (float*)(base + 69206016);                      //  2,097,152 (re||im)
    unsigned short* recO = (unsigned short*)(base + 71303168);      //  8,388,608
    unsigned short* wT0 = (unsigned short*)(base + 79691776);       //     12,288
    unsigned short* wT1 = (unsigned short*)(base + 79704064);       //      8,192
    unsigned short* wT2 = (unsigned short*)(base + 79712256);
    unsigned short* hT0 = (unsigned short*)(base + 79720448);
    unsigned short* hT1 = (unsigned short*)(base + 79732736);
    unsigned short* hT2 = (unsigned short*)(base + 79740928);
    // total ~79.7 MB

    k_prep<<<1, 256, 0, stream>>>(wW0, wW1, wW2, hW0, hW1, hW2,
                                  wT0, wT1, wT2, hT0, hT1, hT2);
    k_wbtfw<<<1024, 256, 0, stream>>>(x, wT0, wb0, wT1, wb1, wT2, wb2, wb_bf, tfwM);
    k_hb_mlp2<<<512, 256, 0, stream>>>(tfwM, hT0, hb0, hT1, hb1, hT2, hb2, hb_bf);
    k_tfhw3<<<1024, 256, 0, stream>>>(tfwM, hb_bf, tfhw_p);
    k_psum<<<1024, 256, 0, stream>>>(tfhw_p, tfhw, 4, 524288);
    k_proc2<<<512, 256, 0, stream>>>(tfhw, Wf_re, Wf_im, proc_p);
    k_psum_procT<<<1024, 256, 0, stream>>>(proc_p, procT);
    k_rec4<<<1024, 256, 0, stream>>>(procT, hb_bf, recO);
    k_final4<<<4096, 256, 0, stream>>>(x, wb_bf, recO, mw, mbv, scw, scb, (float*)d_out);
}

// Round 10
// 184.732 us; speedup vs baseline: 1.5780x; 1.0095x over previous
//
#include <hip/hip_runtime.h>
#include <math.h>

// B=4, C=64, OUT=64, H=256, W=256, M1=32, M2=32, HID=64, COORD=65

typedef __attribute__((ext_vector_type(8))) short bf16x8;
typedef __attribute__((ext_vector_type(4))) float f32x4;

// Fast exact-erf GELU: Abramowitz-Stegun 7.1.26, |eps_erf| <= 1.5e-7.
__device__ __forceinline__ float gelu_f(float v) {
    const float u = v * 0.70710678118654752440f;
    const float xa = fabsf(u);
    const float t = __builtin_amdgcn_rcpf(fmaf(0.3275911f, xa, 1.0f));
    float p = fmaf(1.061405429f, t, -1.453152027f);
    p = fmaf(p, t, 1.421413741f);
    p = fmaf(p, t, -0.284496736f);
    p = fmaf(p, t, 0.254829592f);
    p *= t;
    const float e = __expf(-xa * xa);
    float erfv = fmaf(-p, e, 1.0f);
    erfv = (u < 0.0f) ? -erfv : erfv;
    return 0.5f * v * (1.0f + erfv);
}

__device__ __forceinline__ unsigned short f2b(float f) {
    union { float f; unsigned int u; } v; v.f = f;
    unsigned int u = v.u + 0x7FFFu + ((v.u >> 16) & 1u);   // RNE
    return (unsigned short)(u >> 16);
}
__device__ __forceinline__ float b2f(unsigned short b) {
    union { unsigned int u; float f; } v; v.u = ((unsigned int)b) << 16;
    return v.f;
}

constexpr int MLD = 104;   // legacy stride for k_hb_mlp2 tiles
constexpr int XLD = 72;    // k_final4 tile stride

// ---------------------------------------------------------------------------
// 4x4 butterfly transpose within 4-lane clusters (lane^1, lane^2).
// ---------------------------------------------------------------------------
__device__ __forceinline__ ushort4 butterfly_xT(const float4 v, int q) {
    const float bx = __shfl_xor(v.x, 1);
    const float by = __shfl_xor(v.y, 1);
    const float bz = __shfl_xor(v.z, 1);
    const float bw = __shfl_xor(v.w, 1);
    float4 s1;
    s1.x = ((q & 1) == 0) ? v.x : by;
    s1.y = ((q & 1) == 0) ? bx  : v.y;
    s1.z = ((q & 1) == 0) ? v.z : bw;
    s1.w = ((q & 1) == 0) ? bz  : v.w;
    const float cx = __shfl_xor(s1.x, 2);
    const float cy = __shfl_xor(s1.y, 2);
    const float cz = __shfl_xor(s1.z, 2);
    const float cw = __shfl_xor(s1.w, 2);
    float4 s2;
    s2.x = ((q & 2) == 0) ? s1.x : cz;
    s2.y = ((q & 2) == 0) ? s1.y : cw;
    s2.z = ((q & 2) == 0) ? cx   : s1.z;
    s2.w = ((q & 2) == 0) ? cy   : s1.w;
    ushort4 u;
    u.x = f2b(s2.x); u.y = f2b(s2.y); u.z = f2b(s2.z); u.w = f2b(s2.w);
    return u;
}

__device__ __forceinline__ void stage_xT(const float* __restrict__ x,
    unsigned short* __restrict__ sA, int b, int h, int w0, int t, int LD)
{
    const int lane = t & 63, wv = t >> 6;
    const int q = lane & 3, wg = lane >> 2;
#pragma unroll
    for (int r = 0; r < 4; ++r) {
        const int cb = (r * 4 + wv) * 4;
        const float4 v = *(const float4*)&x[((size_t)(b * 64 + cb + q) * 256 + h) * 256 + w0 + wg * 4];
        const ushort4 u = butterfly_xT(v, q);
        *(ushort4*)&sA[(wg * 4 + q) * LD + cb] = u;
    }
}

// ---------------------------------------------------------------------------
// K_prep: transpose + bf16-convert MLP weights. wT[o][k] = W[k][o]. K0 pad->96.
// ---------------------------------------------------------------------------
__global__ void k_prep(const float* __restrict__ wW0, const float* __restrict__ wW1,
                       const float* __restrict__ wW2,
                       const float* __restrict__ hW0, const float* __restrict__ hW1,
                       const float* __restrict__ hW2,
                       unsigned short* __restrict__ wT0, unsigned short* __restrict__ wT1,
                       unsigned short* __restrict__ wT2,
                       unsigned short* __restrict__ hT0, unsigned short* __restrict__ hT1,
                       unsigned short* __restrict__ hT2)
{
    const int t = threadIdx.x;
    for (int idx = t; idx < 64 * 96; idx += 256) {
        const int o = idx / 96, k = idx % 96;
        wT0[idx] = (k < 65) ? f2b(wW0[k * 64 + o]) : (unsigned short)0;
        hT0[idx] = (k < 65) ? f2b(hW0[k * 64 + o]) : (unsigned short)0;
    }
    for (int idx = t; idx < 4096; idx += 256) {
        const int o = idx >> 6, k = idx & 63;
        wT1[idx] = f2b(wW1[k * 64 + o]);
        wT2[idx] = f2b(wW2[k * 64 + o]);
        hT1[idx] = f2b(hW1[k * 64 + o]);
        hT2[idx] = f2b(hW2[k * 64 + o]);
    }
}

// generic partial-sum
__global__ __launch_bounds__(256) void k_psum(const float* __restrict__ src,
                                              float* __restrict__ dst,
                                              int nparts, int part_stride)
{
    const int i = (blockIdx.x * 256 + threadIdx.x) * 4;
    float4 acc = *(const float4*)&src[i];
    for (int p = 1; p < nparts; ++p) {
        const float4 v = *(const float4*)&src[(size_t)p * part_stride + i];
        acc.x += v.x; acc.y += v.y; acc.z += v.z; acc.w += v.w;
    }
    *(float4*)&dst[i] = acc;
}

// psum for proc + repack to procT[((b*32+m)*32+k)*64+o] (re || im at +262144).
__global__ __launch_bounds__(256) void k_psum_procT(const float* __restrict__ src,
                                                    float* __restrict__ dst)
{
    const int idx = blockIdx.x * 256 + threadIdx.x;
    const int o = idx & 63, k = (idx >> 6) & 31, m = (idx >> 11) & 31, b = idx >> 16;
    const size_t in = (size_t)(b * 64 + o) * 1024 + k * 32 + m;
    const float re = src[in] + src[524288 + in];
    const float im = src[262144 + in] + src[524288 + 262144 + in];
    dst[idx] = re;
    dst[262144 + idx] = im;
}

// ---------------------------------------------------------------------------
// Legacy (stride-104) MLP layer helpers for k_hb_mlp2
// ---------------------------------------------------------------------------
template<bool GELU, int NKC>
__device__ __forceinline__ void mfma_layer(
    const unsigned short* __restrict__ sW,
    const unsigned short* __restrict__ sAct,
    unsigned short* __restrict__ dst,
    const float* __restrict__ bias, int lane, int wv)
{
    const int arow = lane & 15;
    const int koff = (lane >> 4) * 8;
    const int crow = 16 * wv + (lane >> 4) * 4;
    const f32x4 zero = {0.f, 0.f, 0.f, 0.f};
    f32x4 acc[4] = {zero, zero, zero, zero};
#pragma unroll
    for (int kc = 0; kc < NKC; ++kc) {
        const bf16x8 a = *(const bf16x8*)&sW[(16 * wv + arow) * MLD + kc * 32 + koff];
#pragma unroll
        for (int nt = 0; nt < 4; ++nt) {
            const bf16x8 b = *(const bf16x8*)&sAct[(nt * 16 + arow) * MLD + kc * 32 + koff];
            acc[nt] = __builtin_amdgcn_mfma_f32_16x16x32_bf16(a, b, acc[nt], 0, 0, 0);
        }
    }
    const float4 bv = *(const float4*)&bias[crow];
#pragma unroll
    for (int nt = 0; nt < 4; ++nt) {
        const int px = nt * 16 + arow;
        float v0 = acc[nt][0] + bv.x;
        float v1 = acc[nt][1] + bv.y;
        float v2 = acc[nt][2] + bv.z;
        float v3 = acc[nt][3] + bv.w;
        if (GELU) { v0 = gelu_f(v0); v1 = gelu_f(v1); v2 = gelu_f(v2); v3 = gelu_f(v3); }
        ushort4 u;
        u.x = f2b(v0); u.y = f2b(v1); u.z = f2b(v2); u.w = f2b(v3);
        *(ushort4*)&dst[px * MLD + crow] = u;
    }
}

__device__ __forceinline__ void stage_wT96(const unsigned short* __restrict__ src,
                                           unsigned short* __restrict__ sW, int t) {
#pragma unroll
    for (int r = 0; r < 3; ++r) {
        const int idx = r * 256 + t;
        const int row = idx / 12, f = idx % 12;
        *(uint4*)&sW[row * MLD + f * 8] = *(const uint4*)&src[row * 96 + f * 8];
    }
}
__device__ __forceinline__ void stage_wT64(const unsigned short* __restrict__ src,
                                           unsigned short* __restrict__ sW, int t) {
#pragma unroll
    for (int r = 0; r < 2; ++r) {
        const int idx = r * 256 + t;
        const int row = idx >> 3, f = idx & 7;
        *(uint4*)&sW[row * MLD + f * 8] = *(const uint4*)&src[row * 64 + f * 8];
    }
}

// ---------------------------------------------------------------------------
// Swizzled (stride-96) MLP layer helpers for k_wbtfw.
// Swizzle rule (per row): 16B-chunk ch<8 -> ch^(row&7); ch>=8 -> 8+((ch-8)^(row&3)).
// Applied identically on every write and read of a tile (rule #21).
// ---------------------------------------------------------------------------
template<bool GELU, int NKC>
__device__ __forceinline__ void mfma_layer_s(
    const unsigned short* __restrict__ sW,
    const unsigned short* __restrict__ sAct,
    unsigned short* __restrict__ dst,
    const float* __restrict__ bias, int lane, int wv)
{
    const int arow = lane & 15;
    const int g = lane >> 4;
    const int crow = 16 * wv + g * 4;
    const int sx7 = arow & 7, sx3 = arow & 3;   // row-invariant swizzle keys
    const f32x4 zero = {0.f, 0.f, 0.f, 0.f};
    f32x4 acc[4] = {zero, zero, zero, zero};
#pragma unroll
    for (int kc = 0; kc < NKC; ++kc) {
        const int chraw = kc * 4 + g;
        const int ch = (chraw < 8) ? (chraw ^ sx7) : (8 + ((chraw - 8) ^ sx3));
        const bf16x8 a = *(const bf16x8*)&sW[(16 * wv + arow) * 96 + ch * 8];
#pragma unroll
        for (int nt = 0; nt < 4; ++nt) {
            const bf16x8 b = *(const bf16x8*)&sAct[(nt * 16 + arow) * 96 + ch * 8];
            acc[nt] = __builtin_amdgcn_mfma_f32_16x16x32_bf16(a, b, acc[nt], 0, 0, 0);
        }
    }
    const float4 bv = *(const float4*)&bias[crow];
    const int chw = (crow >> 3) ^ sx7;
#pragma unroll
    for (int nt = 0; nt < 4; ++nt) {
        const int px = nt * 16 + arow;
        float v0 = acc[nt][0] + bv.x;
        float v1 = acc[nt][1] + bv.y;
        float v2 = acc[nt][2] + bv.z;
        float v3 = acc[nt][3] + bv.w;
        if (GELU) { v0 = gelu_f(v0); v1 = gelu_f(v1); v2 = gelu_f(v2); v3 = gelu_f(v3); }
        ushort4 u;
        u.x = f2b(v0); u.y = f2b(v1); u.z = f2b(v2); u.w = f2b(v3);
        *(ushort4*)&dst[px * 96 + chw * 8 + (crow & 7)] = u;
    }
}

__device__ __forceinline__ void stage_wT96_s(const unsigned short* __restrict__ src,
                                             unsigned short* __restrict__ sW, int t) {
#pragma unroll
    for (int r = 0; r < 3; ++r) {
        const int idx = r * 256 + t;
        const int row = idx / 12, f = idx % 12;
        const int ch = (f < 8) ? (f ^ (row & 7)) : (8 + ((f - 8) ^ (row & 3)));
        *(uint4*)&sW[row * 96 + ch * 8] = *(const uint4*)&src[row * 96 + f * 8];
    }
}
__device__ __forceinline__ void stage_wT64_s(const unsigned short* __restrict__ src,
                                             unsigned short* __restrict__ sW, int t) {
#pragma unroll
    for (int r = 0; r < 2; ++r) {
        const int idx = r * 256 + t;
        const int row = idx >> 3, f = idx & 7;
        *(uint4*)&sW[row * 96 + ((f ^ (row & 7)) << 3)] = *(const uint4*)&src[row * 64 + f * 8];
    }
}

// ---------------------------------------------------------------------------
// K1+K2 fused: wb MLP + tfw, swizzled LDS (53,248 B -> 3 blocks/CU).
// grid = B*H (1024), 256 threads.
// ---------------------------------------------------------------------------
__global__ __launch_bounds__(256) void k_wbtfw(
    const float* __restrict__ x,
    const unsigned short* __restrict__ wT0, const float* __restrict__ b0,
    const unsigned short* __restrict__ wT1, const float* __restrict__ b1,
    const unsigned short* __restrict__ wT2, const float* __restrict__ b2,
    unsigned short* __restrict__ wb_bf, float* __restrict__ tfwM)
{
    __shared__ __align__(16) unsigned short smem[26624];  // 53,248 B
    unsigned short* sA   = smem;              // [64][96] swizzled
    unsigned short* sB   = smem + 6144;       // [64][96] swizzled
    unsigned short* sW   = smem + 12288;      // [64][96] swizzled weights
    unsigned short* sXt  = smem + 18432;      // [64][64] swizzled x rows
    unsigned short* sWBt = smem + 22528;      // [64][64] swizzled wb^T rows

    const int bh = blockIdx.x;
    const int b = bh >> 8, h = bh & 255;
    const int t = threadIdx.x;
    const int lane = t & 63, wv = t >> 6;
    const int arow = lane & 15, g = lane >> 4;
    const int crow = 16 * wv + g * 4;
    const int sx7 = arow & 7;
    const f32x4 zero = {0.f, 0.f, 0.f, 0.f};

    f32x4 atf[4] = {zero, zero, zero, zero};   // tfw accumulator across tiles

    for (int wq = 0; wq < 4; ++wq) {
        const int w0 = wq * 64;
        __syncthreads();
        // dual-stage x: sXt[c][w] + sA[px][c] (butterfly), both swizzled
        {
            const int q = lane & 3, wg = lane >> 2;
#pragma unroll
            for (int r = 0; r < 4; ++r) {
                const int cb = 16 * r + 4 * wv;
                const int c = cb + q;
                const float4 v = *(const float4*)&x[((size_t)(b * 64 + c) * 256 + h) * 256 + w0 + wg * 4];
                ushort4 ux;
                ux.x = f2b(v.x); ux.y = f2b(v.y); ux.z = f2b(v.z); ux.w = f2b(v.w);
                const int chx = (wg >> 1) ^ (c & 7);
                *(ushort4*)&sXt[c * 64 + chx * 8 + 4 * (wg & 1)] = ux;
                const ushort4 u = butterfly_xT(v, q);
                const int row = wg * 4 + q;   // == lane
                const int cha = (cb >> 3) ^ (row & 7);
                *(ushort4*)&sA[row * 96 + cha * 8 + (cb & 7)] = u;
            }
        }
        if (t < 64) {
            const uint4 z = {0, 0, 0, 0};
#pragma unroll
            for (int j = 0; j < 4; ++j)
                *(uint4*)&sA[t * 96 + (8 + (j ^ (t & 3))) * 8] = z;
            sA[t * 96 + (8 + (t & 3)) * 8] = f2b((float)(w0 + t) * (2.0f / 255.0f) - 1.0f);
        }
        stage_wT96_s(wT0, sW, t);
        __syncthreads();
        mfma_layer_s<true, 3>(sW, sA, sB, b0, lane, wv);
        __syncthreads();
        stage_wT64_s(wT1, sW, t);
        __syncthreads();
        mfma_layer_s<true, 2>(sW, sB, sA, b1, lane, wv);
        __syncthreads();
        stage_wT64_s(wT2, sW, t);
        __syncthreads();
        // layer 2 inline: regs -> sB [px][o] and sWBt [o][px], swizzled
        {
            f32x4 acc[4] = {zero, zero, zero, zero};
#pragma unroll
            for (int kc = 0; kc < 2; ++kc) {
                const int ch = (kc * 4 + g) ^ sx7;
                const bf16x8 a = *(const bf16x8*)&sW[(16 * wv + arow) * 96 + ch * 8];
#pragma unroll
                for (int nt = 0; nt < 4; ++nt) {
                    const bf16x8 bb = *(const bf16x8*)&sA[(nt * 16 + arow) * 96 + ch * 8];
                    acc[nt] = __builtin_amdgcn_mfma_f32_16x16x32_bf16(a, bb, acc[nt], 0, 0, 0);
                }
            }
            const float4 bv = *(const float4*)&b2[crow];
            const int chw = (crow >> 3) ^ sx7;
#pragma unroll
            for (int nt = 0; nt < 4; ++nt) {
                const int px = nt * 16 + arow;
                ushort4 u;
                u.x = f2b(acc[nt][0] + bv.x);
                u.y = f2b(acc[nt][1] + bv.y);
                u.z = f2b(acc[nt][2] + bv.z);
                u.w = f2b(acc[nt][3] + bv.w);
                *(ushort4*)&sB[px * 96 + chw * 8 + (crow & 7)] = u;
                const int ph = px >> 3, pl = px & 7;
                sWBt[(crow + 0) * 64 + ((ph ^ ((crow + 0) & 7)) << 3) + pl] = u.x;
                sWBt[(crow + 1) * 64 + ((ph ^ ((crow + 1) & 7)) << 3) + pl] = u.y;
                sWBt[(crow + 2) * 64 + ((ph ^ ((crow + 2) & 7)) << 3) + pl] = u.z;
                sWBt[(crow + 3) * 64 + ((ph ^ ((crow + 3) & 7)) << 3) + pl] = u.w;
            }
        }
        __syncthreads();
        // wb_bf coalesced write (swizzled read) + tfw partial MFMA
        const size_t pixbase = (size_t)(b * 256 + h) * 256 + w0;
#pragma unroll
        for (int r = 0; r < 2; ++r) {
            const int idx = r * 256 + t;
            const int px = idx >> 3, f = idx & 7;
            *(uint4*)&wb_bf[(pixbase + px) * 64 + f * 8] =
                *(const uint4*)&sB[px * 96 + ((f ^ (px & 7)) << 3)];
        }
#pragma unroll
        for (int kc = 0; kc < 2; ++kc) {
            const int ch = (kc * 4 + g) ^ sx7;
            const bf16x8 a = *(const bf16x8*)&sWBt[(16 * wv + arow) * 64 + ch * 8];
#pragma unroll
            for (int nt = 0; nt < 4; ++nt) {
                const bf16x8 bb = *(const bf16x8*)&sXt[(nt * 16 + arow) * 64 + ch * 8];
                atf[nt] = __builtin_amdgcn_mfma_f32_16x16x32_bf16(a, bb, atf[nt], 0, 0, 0);
            }
        }
    }

    // epilogue: scatter D[mo][c] -> f32 LDS [mo][68], coalesced tfwM write
    __syncthreads();
    float* sF = (float*)smem;   // 17,408 B fits in sA+sB region (24,576 B)
#pragma unroll
    for (int nt = 0; nt < 4; ++nt) {
        const int c = nt * 16 + arow;
#pragma unroll
        for (int j = 0; j < 4; ++j)
            sF[(crow + j) * 68 + c] = atf[nt][j];
    }
    __syncthreads();
#pragma unroll
    for (int r = 0; r < 4; ++r) {
        const int idx = r * 256 + t;
        const int m = idx >> 5, gg = idx & 31;
        float4 v;
        v.x = sF[m * 68 + gg * 2];
        v.y = sF[(m + 32) * 68 + gg * 2];
        v.z = sF[m * 68 + gg * 2 + 1];
        v.w = sF[(m + 32) * 68 + gg * 2 + 1];
        *(float4*)&tfwM[((size_t)(b * 32 + m) * 256 + h) * 128 + gg * 4] = v;
    }
}

// K3: hb basis via MFMA. grid = B*M2*4.
__global__ __launch_bounds__(256) void k_hb_mlp2(
    const float* __restrict__ tfwM,
    const unsigned short* __restrict__ hT0, const float* __restrict__ b0,
    const unsigned short* __restrict__ hT1, const float* __restrict__ b1,
    const unsigned short* __restrict__ hT2, const float* __restrict__ b2,
    unsigned short* __restrict__ hb_bf)
{
    __shared__ __align__(16) unsigned short sA[64 * MLD];
    __shared__ __align__(16) unsigned short sB[64 * MLD];
    __shared__ __align__(16) unsigned short sW[65 * MLD];
    const int blk = blockIdx.x;
    const int bm = blk >> 2, hq = blk & 3;
    const int h0 = hq * 64;
    const int t = threadIdx.x;
    const int lane = t & 63, wv = t >> 6;

#pragma unroll
    for (int r = 0; r < 4; ++r) {
        const int idx = r * 256 + t;
        const int p = idx >> 4, f = idx & 15;
        const float* src = &tfwM[(size_t)(bm * 256 + h0 + p) * 128 + f * 8];
        const float4 u0 = *(const float4*)&src[0];
        const float4 u1 = *(const float4*)&src[4];
        ushort4 u;
        u.x = f2b(u0.x); u.y = f2b(u0.z); u.z = f2b(u1.x); u.w = f2b(u1.z);
        *(ushort4*)&sA[p * MLD + f * 4] = u;
    }
    if (t < 64) {
        const uint4 z = {0, 0, 0, 0};
        *(uint4*)&sA[t * MLD + 64] = z;
        *(uint4*)&sA[t * MLD + 72] = z;
        *(uint4*)&sA[t * MLD + 80] = z;
        *(uint4*)&sA[t * MLD + 88] = z;
        sA[t * MLD + 64] = f2b((float)(h0 + t) * (2.0f / 255.0f) - 1.0f);
    }
    stage_wT96(hT0, sW, t);
    __syncthreads();
    mfma_layer<true, 3>(sW, sA, sB, b0, lane, wv);
    __syncthreads();
    stage_wT64(hT1, sW, t);
    __syncthreads();
    mfma_layer<true, 2>(sW, sB, sA, b1, lane, wv);
    __syncthreads();
    stage_wT64(hT2, sW, t);
    __syncthreads();
    mfma_layer<false, 2>(sW, sA, sB, b2, lane, wv);
    __syncthreads();

    const size_t pixbase = (size_t)bm * 256 + h0;
#pragma unroll
    for (int r = 0; r < 2; ++r) {
        const int idx = r * 256 + t;
        const int px = idx >> 3, f = idx & 7;
        *(uint4*)&hb_bf[(pixbase + px) * 64 + f * 8] = *(const uint4*)&sB[px * MLD + f * 8];
    }
}

// K4: tfhw partials. grid = 1024: (bm, chalf, hq).
__global__ __launch_bounds__(256) void k_tfhw3(
    const float* __restrict__ tfwM,
    const unsigned short* __restrict__ hb_bf,
    float* __restrict__ tfhw_p)
{
    __shared__ float hr[64 * 32];
    __shared__ float hi2[64 * 32];
    __shared__ float slab[32 * 64];
    const int blk = blockIdx.x;
    const int bm = blk >> 3, chalf = (blk >> 2) & 1, hq = blk & 3;
    const int b = bm >> 5, m = bm & 31;
    const int t = threadIdx.x;
#pragma unroll
    for (int r = 0; r < 2; ++r) {
        const int q = r * 256 + t;
        const int hl = q >> 3, f = q & 7;
        const uint4 raw = *(const uint4*)&hb_bf[((size_t)bm * 256 + hq * 64 + hl) * 64 + f * 8];
        const unsigned short* us = (const unsigned short*)&raw;
        float v[8];
#pragma unroll
        for (int j = 0; j < 8; ++j) v[j] = b2f(us[j]);
        float* dst = (f < 4) ? &hr[hl * 32 + f * 8] : &hi2[hl * 32 + (f - 4) * 8];
        float4 lo; lo.x = v[0]; lo.y = v[1]; lo.z = v[2]; lo.w = v[3];
        float4 hi; hi.x = v[4]; hi.y = v[5]; hi.z = v[6]; hi.w = v[7];
        *(float4*)&dst[0] = lo;
        *(float4*)&dst[4] = hi;
    }
    const int k = t & 31, cq = t >> 5;
    float accr[4] = {0.f, 0.f, 0.f, 0.f}, acci[4] = {0.f, 0.f, 0.f, 0.f};
    const size_t tbase = (size_t)bm * 32768;
    for (int ht = 0; ht < 2; ++ht) {
        __syncthreads();
#pragma unroll
        for (int r = 0; r < 2; ++r) {
            const int q = r * 256 + t;
            const int hl = q >> 3, f = q & 7;
            *(float4*)&slab[hl * 64 + f * 4] =
                *(const float4*)&tfwM[tbase + (size_t)(hq * 64 + ht * 32 + hl) * 128 + chalf * 64 + f * 4];
        }
        __syncthreads();
#pragma unroll 8
        for (int hl = 0; hl < 32; ++hl) {
            const float hrv = hr[(ht * 32 + hl) * 32 + k];
            const float hiv = hi2[(ht * 32 + hl) * 32 + k];
            const float4 u0 = *(const float4*)&slab[hl * 64 + cq * 8];
            const float4 u1 = *(const float4*)&slab[hl * 64 + cq * 8 + 4];
            accr[0] = fmaf(u0.x, hrv, fmaf(-u0.y, hiv, accr[0]));
            acci[0] = fmaf(u0.x, hiv, fmaf( u0.y, hrv, acci[0]));
            accr[1] = fmaf(u0.z, hrv, fmaf(-u0.w, hiv, accr[1]));
            acci[1] = fmaf(u0.z, hiv, fmaf( u0.w, hrv, acci[1]));
            accr[2] = fmaf(u1.x, hrv, fmaf(-u1.y, hiv, accr[2]));
            acci[2] = fmaf(u1.x, hiv, fmaf( u1.y, hrv, acci[2]));
            accr[3] = fmaf(u1.z, hrv, fmaf(-u1.w, hiv, accr[3]));
            acci[3] = fmaf(u1.z, hiv, fmaf( u1.w, hrv, acci[3]));
        }
    }
    float* tp = tfhw_p + (size_t)hq * 524288;
#pragma unroll
    for (int i = 0; i < 4; ++i) {
        const int c = chalf * 32 + cq * 4 + i;
        const size_t po = ((size_t)(b * 64 + c) * 32 + k) * 32 + m;
        tp[po] = accr[i];
        tp[262144 + po] = acci[i];
    }
}

// K5: proc partials. grid = 512: (o, kq, chalf).
__global__ __launch_bounds__(256) void k_proc2(
    const float* __restrict__ tfhw,
    const float* __restrict__ Wf_re, const float* __restrict__ Wf_im,
    float* __restrict__ proc_p)
{
    const int blk = blockIdx.x;
    const int o = blk >> 3, kq = (blk >> 1) & 3, chalf = blk & 1;
    const int t = threadIdx.x;
    const int mo = kq * 256 + t;
    const float* tre = tfhw;
    const float* tim = tfhw + 262144;
    float accr[4] = {0.f, 0.f, 0.f, 0.f}, acci[4] = {0.f, 0.f, 0.f, 0.f};
    for (int cc = 0; cc < 32; ++cc) {
        const int c = chalf * 32 + cc;
        const float wfr = Wf_re[(size_t)(c * 64 + o) * 1024 + mo];
        const float wfi = Wf_im[(size_t)(c * 64 + o) * 1024 + mo];
#pragma unroll
        for (int bb = 0; bb < 4; ++bb) {
            const float tr = tre[(size_t)(bb * 64 + c) * 1024 + mo];
            const float ti = tim[(size_t)(bb * 64 + c) * 1024 + mo];
            accr[bb] = fmaf(tr, wfr, fmaf(-ti, wfi, accr[bb]));
            acci[bb] = fmaf(tr, wfi, fmaf(ti, wfr, acci[bb]));
        }
    }
    float* pp = proc_p + (size_t)chalf * 524288;
#pragma unroll
    for (int bb = 0; bb < 4; ++bb) {
        pp[(size_t)(bb * 64 + o) * 1024 + mo] = accr[bb];
        pp[262144 + (size_t)(bb * 64 + o) * 1024 + mo] = acci[bb];
    }
}

// K6: recO bf16. grid = 1024: (bm, hq8). Coalesced procT reads.
__global__ __launch_bounds__(256) void k_rec4(
    const float* __restrict__ procT,
    const unsigned short* __restrict__ hb_bf,
    unsigned short* __restrict__ recO)
{
    __shared__ float lhr[32 * 32];
    __shared__ float lhi[32 * 32];
    const int blk = blockIdx.x;
    const int bm = blk >> 3, hq = blk & 7;
    const int b = bm >> 5, m = bm & 31;
    const int t = threadIdx.x;
    {
        const int hl = t >> 3, f = t & 7;
        const uint4 raw = *(const uint4*)&hb_bf[((size_t)bm * 256 + hq * 32 + hl) * 64 + f * 8];
        const unsigned short* us = (const unsigned short*)&raw;
        float v[8];
#pragma unroll
        for (int j = 0; j < 8; ++j) v[j] = b2f(us[j]);
        float* dst = (f < 4) ? &lhr[hl * 32 + f * 8] : &lhi[hl * 32 + (f - 4) * 8];
        float4 lo; lo.x = v[0]; lo.y = v[1]; lo.z = v[2]; lo.w = v[3];
        float4 hi; hi.x = v[4]; hi.y = v[5]; hi.z = v[6]; hi.w = v[7];
        *(float4*)&dst[0] = lo;
        *(float4*)&dst[4] = hi;
    }
    const int o = t & 63, hg = t >> 6;
    const float* pr = procT + (size_t)(b * 32 + m) * 2048 + o;
    const float* pi = pr + 262144;
    float Pr[32], Pi[32];
#pragma unroll
    for (int k = 0; k < 32; ++k) {
        Pr[k] = pr[k * 64];
        Pi[k] = pi[k * 64];
    }
    __syncthreads();
    for (int hh = 0; hh < 8; ++hh) {
        const int hl = hg * 8 + hh;
        float ar = 0.f, ai = 0.f;
#pragma unroll
        for (int k4 = 0; k4 < 8; ++k4) {
            const float4 hr4 = *(const float4*)&lhr[hl * 32 + k4 * 4];
            const float4 hi4 = *(const float4*)&lhi[hl * 32 + k4 * 4];
            ar = fmaf(Pr[k4*4+0], hr4.x, fmaf(Pi[k4*4+0], hi4.x, ar));
            ai = fmaf(Pi[k4*4+0], hr4.x, fmaf(-Pr[k4*4+0], hi4.x, ai));
            ar = fmaf(Pr[k4*4+1], hr4.y, fmaf(Pi[k4*4+1], hi4.y, ar));
            ai = fmaf(Pi[k4*4+1], hr4.y, fmaf(-Pr[k4*4+1], hi4.y, ai));
            ar = fmaf(Pr[k4*4+2], hr4.z, fmaf(Pi[k4*4+2], hi4.z, ar));
            ai = fmaf(Pi[k4*4+2], hr4.z, fmaf(-Pr[k4*4+2], hi4.z, ai));
            ar = fmaf(Pr[k4*4+3], hr4.w, fmaf(Pi[k4*4+3], hi4.w, ar));
            ai = fmaf(Pi[k4*4+3], hr4.w, fmaf(-Pr[k4*4+3], hi4.w, ai));
        }
        const int h = hq * 32 + hl;
        const size_t rb = ((size_t)(b * 256 + h) * 64 + o) * 64;
        recO[rb + m]      = f2b(ar);
        recO[rb + 32 + m] = f2b(ai);
    }
}

// K7: MFMA fused final. grid = B*H*4.
__global__ __launch_bounds__(256) void k_final4(
    const float* __restrict__ x,
    const unsigned short* __restrict__ wb_bf,
    const unsigned short* __restrict__ recO,
    const float* __restrict__ mw, const float* __restrict__ mb,
    const float* __restrict__ scw, const float* __restrict__ scb,
    float* __restrict__ out)
{
    constexpr int LD = 72;
    __shared__ __align__(16) unsigned short sWb[64 * LD];
    __shared__ __align__(16) unsigned short sR [64 * LD];
    __shared__ __align__(16) unsigned short sX [64 * LD];
    __shared__ __align__(16) unsigned short sS [64 * LD];
    const int blk = blockIdx.x;
    const int b = blk >> 10, h = (blk >> 2) & 255, wq = blk & 3;
    const int w0 = wq * 64;
    const int t = threadIdx.x;
    const int lane = t & 63, wv = t >> 6;
    const size_t pixbase = (size_t)(b * 256 + h) * 256 + w0;

#pragma unroll
    for (int r = 0; r < 2; ++r) {
        const int idx = r * 256 + t;
        const int px = idx >> 3, f = idx & 7;
        *(uint4*)&sWb[px * LD + f * 8] = *(const uint4*)&wb_bf[(pixbase + px) * 64 + f * 8];
    }
    const size_t recbase = (size_t)(b * 256 + h) * 4096;
#pragma unroll
    for (int r = 0; r < 2; ++r) {
        const int idx = r * 256 + t;
        const int o = idx >> 3, f = idx & 7;
        *(uint4*)&sR[o * LD + f * 8] = *(const uint4*)&recO[recbase + (size_t)o * 64 + f * 8];
    }
    stage_xT(x, sX, b, h, w0, t, LD);
    __syncthreads();

    const int arow = lane & 15;
    const int koff = (lane >> 4) * 8;
    const f32x4 zero = {0.f, 0.f, 0.f, 0.f};

    f32x4 accA[4] = {zero, zero, zero, zero};
#pragma unroll
    for (int kc = 0; kc < 2; ++kc) {
        const bf16x8 a = *(const bf16x8*)&sR[(16 * wv + arow) * LD + kc * 32 + koff];
#pragma unroll
        for (int nt = 0; nt < 4; ++nt) {
            const bf16x8 bb = *(const bf16x8*)&sWb[(nt * 16 + arow) * LD + kc * 32 + koff];
            accA[nt] = __builtin_amdgcn_mfma_f32_16x16x32_bf16(a, bb, accA[nt], 0, 0, 0);
        }
    }
    __syncthreads();

    const int crow = 16 * wv + (lane >> 4) * 4;
#pragma unroll
    for (int nt = 0; nt < 4; ++nt) {
        const int px = nt * 16 + arow;
#pragma unroll
        for (int j = 0; j < 4; ++j)
            sS[px * LD + crow + j] = f2b(accA[nt][j] * (1.0f / 65536.0f));
    }
#pragma unroll
    for (int r = 0; r < 4; ++r) {
        const int idx = r * 256 + t;
        const int o = idx >> 4, cq = idx & 15;
        const float4 v1 = *(const float4*)&mw[o * 64 + cq * 4];
        ushort4 u1;
        u1.x = f2b(v1.x); u1.y = f2b(v1.y); u1.z = f2b(v1.z); u1.w = f2b(v1.w);
        *(ushort4*)&sWb[o * LD + cq * 4] = u1;
        const float4 v2 = *(const float4*)&scw[o * 64 + cq * 4];
        ushort4 u2;
        u2.x = f2b(v2.x); u2.y = f2b(v2.y); u2.z = f2b(v2.z); u2.w = f2b(v2.w);
        *(ushort4*)&sR[o * LD + cq * 4] = u2;
    }
    __syncthreads();

    f32x4 accB[4] = {zero, zero, zero, zero};
    f32x4 accC[4] = {zero, zero, zero, zero};
#pragma unroll
    for (int kc = 0; kc < 2; ++kc) {
        const bf16x8 am = *(const bf16x8*)&sWb[(16 * wv + arow) * LD + kc * 32 + koff];
        const bf16x8 as = *(const bf16x8*)&sR [(16 * wv + arow) * LD + kc * 32 + koff];
#pragma unroll
        for (int nt = 0; nt < 4; ++nt) {
            const bf16x8 bs = *(const bf16x8*)&sS[(nt * 16 + arow) * LD + kc * 32 + koff];
            const bf16x8 bx = *(const bf16x8*)&sX[(nt * 16 + arow) * LD + kc * 32 + koff];
            accB[nt] = __builtin_amdgcn_mfma_f32_16x16x32_bf16(am, bs, accB[nt], 0, 0, 0);
            accC[nt] = __builtin_amdgcn_mfma_f32_16x16x32_bf16(as, bx, accC[nt], 0, 0, 0);
        }
    }

#pragma unroll
    for (int nt = 0; nt < 4; ++nt) {
        const int px = nt * 16 + arow;
#pragma unroll
        for (int j = 0; j < 4; ++j) {
            const int o = crow + j;
            const float y = gelu_f(accB[nt][j] + mb[o]);
            const float z = y + accC[nt][j] + scb[o];
            out[((size_t)(b * 64 + o) * 256 + h) * 256 + w0 + px] = gelu_f(z);
        }
    }
}

extern "C" void kernel_launch(void* const* d_in, const int* in_sizes, int n_in,
                              void* d_out, int out_size, void* d_ws, size_t ws_size,
                              hipStream_t stream) {
    const float* x    = (const float*)d_in[0];
    const float* wW0  = (const float*)d_in[1];
    const float* wb0  = (const float*)d_in[2];
    const float* wW1  = (const float*)d_in[3];
    const float* wb1  = (const float*)d_in[4];
    const float* wW2  = (const float*)d_in[5];
    const float* wb2  = (const float*)d_in[6];
    const float* hW0  = (const float*)d_in[7];
    const float* hb0  = (const float*)d_in[8];
    const float* hW1  = (const float*)d_in[9];
    const float* hb1  = (const float*)d_in[10];
    const float* hW2  = (const float*)d_in[11];
    const float* hb2  = (const float*)d_in[12];
    const float* Wf_re = (const float*)d_in[13];
    const float* Wf_im = (const float*)d_in[14];
    const float* mw   = (const float*)d_in[15];
    const float* mbv  = (const float*)d_in[16];
    const float* scw  = (const float*)d_in[17];
    const float* scb  = (const float*)d_in[18];

    char* base = (char*)d_ws;
    unsigned short* wb_bf = (unsigned short*)(base + 0);            // 33,554,432
    float* tfwM   = (float*)(base + 33554432);                      // 16,777,216
    unsigned short* hb_bf = (unsigned short*)(base + 50331648);     //  4,194,304
    float* tfhw_p = (float*)(base + 54525952);                      //  8,388,608 (4 parts)
    float* tfhw   = (float*)(base + 62914560);                      //  2,097,152 (re||im)
    float* proc_p = (float*)(base + 65011712);                      //  4,194,304 (2 parts)
    float* procT  = (float*)(base + 69206016);                      //  2,097,152 (re||im)
    unsigned short* recO = (unsigned short*)(base + 71303168);      //  8,388,608
    unsigned short* wT0 = (unsigned short*)(base + 79691776);       //     12,288
    unsigned short* wT1 = (unsigned short*)(base + 79704064);       //      8,192
    unsigned short* wT2 = (unsigned short*)(base + 79712256);
    unsigned short* hT0 = (unsigned short*)(base + 79720448);
    unsigned short* hT1 = (unsigned short*)(base + 79732736);
    unsigned short* hT2 = (unsigned short*)(base + 79740928);
    // total ~79.7 MB

    k_prep<<<1, 256, 0, stream>>>(wW0, wW1, wW2, hW0, hW1, hW2,
                                  wT0, wT1, wT2, hT0, hT1, hT2);
    k_wbtfw<<<1024, 256, 0, stream>>>(x, wT0, wb0, wT1, wb1, wT2, wb2, wb_bf, tfwM);
    k_hb_mlp2<<<512, 256, 0, stream>>>(tfwM, hT0, hb0, hT1, hb1, hT2, hb2, hb_bf);
    k_tfhw3<<<1024, 256, 0, stream>>>(tfwM, hb_bf, tfhw_p);
    k_psum<<<1024, 256, 0, stream>>>(tfhw_p, tfhw, 4, 524288);
    k_proc2<<<512, 256, 0, stream>>>(tfhw, Wf_re, Wf_im, proc_p);
    k_psum_procT<<<1024, 256, 0, stream>>>(proc_p, procT);
    k_rec4<<<1024, 256, 0, stream>>>(procT, hb_bf, recO);
    k_final4<<<4096, 256, 0, stream>>>(x, wb_bf, recO, mw, mbv, scw, scb, (float*)d_out);
}